// Round 7
// baseline (400.766 us; speedup 1.0000x reference)
//
#include <hip/hip_runtime.h>
#include <math.h>

#define BATCH 4
#define SEQ   1024
#define EMB   1024
#define HEADS 16
#define HD    64
#define MTOT  (BATCH*SEQ)   // 4096

typedef float f32x4 __attribute__((ext_vector_type(4)));
typedef short s16x8 __attribute__((ext_vector_type(8)));

// ---- bf16 hi/lo split helpers (RNE) ---------------------------------------
__device__ __forceinline__ unsigned short f2bf(float f) {
    unsigned u = __float_as_uint(f);
    unsigned r = u + 0x7fffu + ((u >> 16) & 1u);
    return (unsigned short)(r >> 16);
}
__device__ __forceinline__ float bf2f(unsigned short h) {
    return __uint_as_float(((unsigned)h) << 16);
}

// ---- conversion kernels ---------------------------------------------------
__global__ __launch_bounds__(256) void convert_x(
    const float* __restrict__ in, unsigned short* __restrict__ hi,
    unsigned short* __restrict__ lo)
{
    size_t base = ((size_t)blockIdx.x << 10) + (threadIdx.x << 2);
    float4 v = *(const float4*)(in + base);
    ushort4 h, l;
    h.x = f2bf(v.x); l.x = f2bf(v.x - bf2f(h.x));
    h.y = f2bf(v.y); l.y = f2bf(v.y - bf2f(h.y));
    h.z = f2bf(v.z); l.z = f2bf(v.z - bf2f(h.z));
    h.w = f2bf(v.w); l.w = f2bf(v.w - bf2f(h.w));
    *(ushort4*)(hi + base) = h;
    *(ushort4*)(lo + base) = l;
}

__global__ __launch_bounds__(256) void convert_w4(
    const float* __restrict__ wq, const float* __restrict__ wk,
    const float* __restrict__ wv, const float* __restrict__ wo,
    unsigned short* __restrict__ hi, unsigned short* __restrict__ lo)
{
    int mi = blockIdx.x >> 10;
    int r  = blockIdx.x & 1023;
    const float* in = (mi == 0) ? wq : (mi == 1) ? wk : (mi == 2) ? wv : wo;
    size_t ib = ((size_t)r << 10) + (threadIdx.x << 2);
    size_t ob = ((size_t)mi << 20) + ib;
    float4 v = *(const float4*)(in + ib);
    ushort4 h, l;
    h.x = f2bf(v.x); l.x = f2bf(v.x - bf2f(h.x));
    h.y = f2bf(v.y); l.y = f2bf(v.y - bf2f(h.y));
    h.z = f2bf(v.z); l.z = f2bf(v.z - bf2f(h.z));
    h.w = f2bf(v.w); l.w = f2bf(v.w - bf2f(h.w));
    *(ushort4*)(hi + ob) = h;
    *(ushort4*)(lo + ob) = l;
}

// ---- split-bf16 MFMA GEMM tile (unchanged) --------------------------------
#define BM  128
#define BN  128
#define BKS 64
#define LDT 72

__device__ __forceinline__ void mfma_gemm_tile(
    const unsigned short* __restrict__ Ahi, const unsigned short* __restrict__ Alo,
    const unsigned short* __restrict__ Bhi, const unsigned short* __restrict__ Blo,
    int m0, int n0, f32x4 acc[4][4])
{
    __shared__ unsigned short As[BM * LDT];
    __shared__ unsigned short Bs[BM * LDT];
    const int tid  = threadIdx.x;
    const int lane = tid & 63;
    const int w    = tid >> 6;
    const int wr   = w >> 1, wc = w & 1;
    const int fr   = lane & 15;
    const int kb   = lane >> 4;

#pragma unroll
    for (int i = 0; i < 4; ++i)
#pragma unroll
        for (int j = 0; j < 4; ++j) acc[i][j] = (f32x4){0.f, 0.f, 0.f, 0.f};

    s16x8 ra[4], rb[4];
#define LOAD_STEP(KT)                                                          \
    {                                                                          \
        int seg = (KT) >> 4;                                                   \
        int k0  = ((KT) & 15) * BKS;                                           \
        const unsigned short* Ap = (seg < 2) ? Ahi : Alo;                      \
        const unsigned short* Bp = (seg == 1) ? Blo : Bhi;                     \
        _Pragma("unroll")                                                      \
        for (int i = 0; i < 4; ++i) {                                          \
            int c = tid + (i << 8);                                            \
            int row = c >> 3, cc = (c & 7) << 3;                               \
            ra[i] = *(const s16x8*)(Ap + ((size_t)(m0 + row) << 10) + k0 + cc);\
            rb[i] = *(const s16x8*)(Bp + ((size_t)(n0 + row) << 10) + k0 + cc);\
        }                                                                      \
    }

    LOAD_STEP(0);
    for (int kt = 0; kt < 48; ++kt) {
        __syncthreads();
#pragma unroll
        for (int i = 0; i < 4; ++i) {
            int c = tid + (i << 8);
            int row = c >> 3, cc = (c & 7) << 3;
            *(s16x8*)&As[row * LDT + cc] = ra[i];
            *(s16x8*)&Bs[row * LDT + cc] = rb[i];
        }
        if (kt + 1 < 48) LOAD_STEP(kt + 1);
        __syncthreads();
#pragma unroll
        for (int kc = 0; kc < 2; ++kc) {
            s16x8 aF[4], bF[4];
#pragma unroll
            for (int i = 0; i < 4; ++i)
                aF[i] = *(const s16x8*)&As[(wr * 64 + i * 16 + fr) * LDT + kc * 32 + kb * 8];
#pragma unroll
            for (int j = 0; j < 4; ++j)
                bF[j] = *(const s16x8*)&Bs[(wc * 64 + j * 16 + fr) * LDT + kc * 32 + kb * 8];
#pragma unroll
            for (int i = 0; i < 4; ++i)
#pragma unroll
                for (int j = 0; j < 4; ++j)
                    acc[i][j] = __builtin_amdgcn_mfma_f32_16x16x32_bf16(
                        aF[i], bF[j], acc[i][j], 0, 0, 0);
        }
    }
#undef LOAD_STEP
}

// QKV: writes Q,K as bf16 hi/lo (b,h,s,d); V transposed hi/lo (b,h,d,s).
__global__ __launch_bounds__(256, 2) void qkv_mfma(
    const unsigned short* __restrict__ xhi, const unsigned short* __restrict__ xlo,
    const unsigned short* __restrict__ whi, const unsigned short* __restrict__ wlo,
    const float* __restrict__ bq, const float* __restrict__ bk,
    const float* __restrict__ bv,
    unsigned short* __restrict__ qhi, unsigned short* __restrict__ qlo,
    unsigned short* __restrict__ khi, unsigned short* __restrict__ klo,
    unsigned short* __restrict__ vthi, unsigned short* __restrict__ vtlo)
{
    const int z = blockIdx.z;
    const unsigned short* Bh = whi + ((size_t)z << 20);
    const unsigned short* Bl = wlo + ((size_t)z << 20);
    const float* bias = (z == 0) ? bq : (z == 1) ? bk : bv;
    const int m0 = blockIdx.y * BM, n0 = blockIdx.x * BN;
    f32x4 acc[4][4];
    mfma_gemm_tile(xhi, xlo, Bh, Bl, m0, n0, acc);

    const int lane = threadIdx.x & 63;
    const int w    = threadIdx.x >> 6;
    const int wr   = w >> 1, wc = w & 1;
    const int fr   = lane & 15;
    const int rg   = lane >> 4;
#pragma unroll
    for (int i = 0; i < 4; ++i)
#pragma unroll
        for (int j = 0; j < 4; ++j) {
            int n = n0 + wc * 64 + j * 16 + fr;
            int h = n >> 6, d = n & 63;
            float bv_ = bias[n];
            int m_base = m0 + wr * 64 + i * 16 + rg * 4;
            int b = m_base >> 10, s0 = m_base & 1023;
            if (z < 2) {
                unsigned short* ph = (z == 0) ? qhi : khi;
                unsigned short* pl = (z == 0) ? qlo : klo;
#pragma unroll
                for (int r = 0; r < 4; ++r) {
                    float v = acc[i][j][r] + bv_;
                    unsigned short hh = f2bf(v);
                    size_t a = ((size_t)((b * HEADS + h) * SEQ + s0 + r)) * HD + d;
                    ph[a] = hh;
                    pl[a] = f2bf(v - bf2f(hh));
                }
            } else {
                ushort4 h4, l4;
                float v0 = acc[i][j][0] + bv_;
                float v1 = acc[i][j][1] + bv_;
                float v2 = acc[i][j][2] + bv_;
                float v3 = acc[i][j][3] + bv_;
                h4.x = f2bf(v0); l4.x = f2bf(v0 - bf2f(h4.x));
                h4.y = f2bf(v1); l4.y = f2bf(v1 - bf2f(h4.y));
                h4.z = f2bf(v2); l4.z = f2bf(v2 - bf2f(h4.z));
                h4.w = f2bf(v3); l4.w = f2bf(v3 - bf2f(h4.w));
                size_t a = ((size_t)((b * HEADS + h) * HD + d)) * SEQ + s0;
                *(ushort4*)(vthi + a) = h4;
                *(ushort4*)(vtlo + a) = l4;
            }
        }
}

// OPROJ (unchanged)
__global__ __launch_bounds__(256, 2) void oproj_mfma(
    const unsigned short* __restrict__ chi, const unsigned short* __restrict__ clo,
    const unsigned short* __restrict__ whi, const unsigned short* __restrict__ wlo,
    const float* __restrict__ bo, float* __restrict__ out)
{
    const unsigned short* Bh = whi + ((size_t)3 << 20);
    const unsigned short* Bl = wlo + ((size_t)3 << 20);
    const int m0 = blockIdx.y * BM, n0 = blockIdx.x * BN;
    f32x4 acc[4][4];
    mfma_gemm_tile(chi, clo, Bh, Bl, m0, n0, acc);

    const int lane = threadIdx.x & 63;
    const int w    = threadIdx.x >> 6;
    const int wr   = w >> 1, wc = w & 1;
    const int fr   = lane & 15;
    const int rg   = lane >> 4;
#pragma unroll
    for (int i = 0; i < 4; ++i)
#pragma unroll
        for (int j = 0; j < 4; ++j) {
            int n = n0 + wc * 64 + j * 16 + fr;
            float bv_ = bo[n];
#pragma unroll
            for (int r = 0; r < 4; ++r) {
                int m = m0 + wr * 64 + i * 16 + rg * 4 + r;
                out[(size_t)m * EMB + n] = acc[i][j][r] + bv_;
            }
        }
}

// ---------------- attention: MFMA with DIRECT-GLOBAL B-fragments -----------
// K (b,h,s,d) and V^T (b,h,d,s) layouts map exactly onto the 16x16x32 B-frag
// pattern (col=lane&15, k=(lane>>4)*8+i), so K/V frags are loaded straight
// from global (L2-resident, XCD-pinned) — no LDS staging, no QK^T barriers.
// Only P transposes through LDS (16x128 bf16 hi/lo, XOR-16 swizzled).
__global__ __launch_bounds__(256, 3) void attn_kernel(
    const unsigned short* __restrict__ qhi, const unsigned short* __restrict__ qlo,
    const unsigned short* __restrict__ khi, const unsigned short* __restrict__ klo,
    const unsigned short* __restrict__ vthi, const unsigned short* __restrict__ vtlo,
    float* __restrict__ attn,
    unsigned short* __restrict__ chi, unsigned short* __restrict__ clo)
{
    __shared__ unsigned short PTh[16 * 128];   // 4 KB
    __shared__ unsigned short PTl[16 * 128];   // 4 KB
    __shared__ float RMAX[4][16];
    __shared__ float RSUM[4][16];

    const int lid = blockIdx.y * gridDim.x + blockIdx.x;  // XCD swizzle
    const int xs  = lid & 7;
    const int jj  = lid >> 3;
    const int bh  = xs * 8 + (jj >> 6);
    const int qt  = jj & 63;

    const int tid  = threadIdx.x;
    const int w    = tid >> 6;
    const int lane = tid & 63;
    const int c    = lane & 15;
    const int g    = lane >> 4;

    const size_t bhS = (size_t)bh * SEQ;

    // Q A-frags (lane holds q-row=c, k-depth=g*8..+7 within 32-blocks)
    s16x8 Qh[2], Ql[2];
    {
        size_t qb = (bhS + qt * 16 + c) * HD + g * 8;
        Qh[0] = *(const s16x8*)(qhi + qb);
        Qh[1] = *(const s16x8*)(qhi + qb + 32);
        Ql[0] = *(const s16x8*)(qlo + qb);
        Ql[1] = *(const s16x8*)(qlo + qb + 32);
    }

    // K B-frag bases: wave w owns k-cols {kt*64 + w*16 + c}
    const unsigned short* Kbh = khi + (bhS + w * 16 + c) * HD + g * 8;
    const unsigned short* Kbl = klo + (bhS + w * 16 + c) * HD + g * 8;

    f32x4 s4[16];
#pragma unroll
    for (int kt = 0; kt < 16; ++kt) s4[kt] = (f32x4){0.f, 0.f, 0.f, 0.f};

    // ---- QK^T: direct-global B-frags, no barriers ----
#pragma unroll
    for (int kt = 0; kt < 16; ++kt) {
        const size_t o = (size_t)kt * 64 * HD;
        s16x8 Bh0 = *(const s16x8*)(Kbh + o);
        s16x8 Bh1 = *(const s16x8*)(Kbh + o + 32);
        s16x8 Bl0 = *(const s16x8*)(Kbl + o);
        s16x8 Bl1 = *(const s16x8*)(Kbl + o + 32);
        s4[kt] = __builtin_amdgcn_mfma_f32_16x16x32_bf16(Qh[0], Bh0, s4[kt], 0, 0, 0);
        s4[kt] = __builtin_amdgcn_mfma_f32_16x16x32_bf16(Qh[1], Bh1, s4[kt], 0, 0, 0);
        s4[kt] = __builtin_amdgcn_mfma_f32_16x16x32_bf16(Qh[0], Bl0, s4[kt], 0, 0, 0);
        s4[kt] = __builtin_amdgcn_mfma_f32_16x16x32_bf16(Qh[1], Bl1, s4[kt], 0, 0, 0);
        s4[kt] = __builtin_amdgcn_mfma_f32_16x16x32_bf16(Ql[0], Bh0, s4[kt], 0, 0, 0);
        s4[kt] = __builtin_amdgcn_mfma_f32_16x16x32_bf16(Ql[1], Bh1, s4[kt], 0, 0, 0);
    }

    // ---- softmax (C layout: lane holds q-rows g*4+r, k-col w*16+c+64*kt) --
    float m_[4], l_[4];
#pragma unroll
    for (int r = 0; r < 4; ++r) {
        float mm = -1e30f;
#pragma unroll
        for (int kt = 0; kt < 16; ++kt) {
            s4[kt][r] *= 0.125f;
            mm = fmaxf(mm, s4[kt][r]);
        }
        m_[r] = mm;
    }
#pragma unroll
    for (int off = 1; off < 16; off <<= 1)
#pragma unroll
        for (int r = 0; r < 4; ++r) m_[r] = fmaxf(m_[r], __shfl_xor(m_[r], off));
    if (c == 0) {
#pragma unroll
        for (int r = 0; r < 4; ++r) RMAX[w][g * 4 + r] = m_[r];
    }
    __syncthreads();
#pragma unroll
    for (int r = 0; r < 4; ++r)
        m_[r] = fmaxf(fmaxf(RMAX[0][g * 4 + r], RMAX[1][g * 4 + r]),
                      fmaxf(RMAX[2][g * 4 + r], RMAX[3][g * 4 + r]));
#pragma unroll
    for (int r = 0; r < 4; ++r) {
        float ss = 0.f;
#pragma unroll
        for (int kt = 0; kt < 16; ++kt) {
            float p = __expf(s4[kt][r] - m_[r]);
            s4[kt][r] = p;
            ss += p;
        }
        l_[r] = ss;
    }
#pragma unroll
    for (int off = 1; off < 16; off <<= 1)
#pragma unroll
        for (int r = 0; r < 4; ++r) l_[r] += __shfl_xor(l_[r], off);
    if (c == 0) {
#pragma unroll
        for (int r = 0; r < 4; ++r) RSUM[w][g * 4 + r] = l_[r];
    }
    __syncthreads();
#pragma unroll
    for (int r = 0; r < 4; ++r)
        l_[r] = 1.f / (RSUM[0][g * 4 + r] + RSUM[1][g * 4 + r] +
                       RSUM[2][g * 4 + r] + RSUM[3][g * 4 + r]);

    // ---- attn write + PV (8 chunks of 128 k) ----
    f32x4 ctx = (f32x4){0.f, 0.f, 0.f, 0.f};
    float* ap = attn + (bhS + qt * 16) * SEQ;
    // V B-frag bases: wave w owns d-cols {w*16 + c}
    const unsigned short* Vbh = vthi + ((size_t)bh * HD + w * 16 + c) * SEQ + g * 8;
    const unsigned short* Vbl = vtlo + ((size_t)bh * HD + w * 16 + c) * SEQ + g * 8;

#pragma unroll
    for (int ct = 0; ct < 8; ++ct) {
        __syncthreads();   // previous chunk's PT reads done
        // normalized P -> attn (nontemporal, 64B runs) + PT hi/lo (swizzled)
#pragma unroll
        for (int kt2 = 0; kt2 < 2; ++kt2) {
            const int ktg = ct * 2 + kt2;
            const int col = kt2 * 64 + w * 16 + c;
            const int chh = col >> 3;
#pragma unroll
            for (int r = 0; r < 4; ++r) {
                const int q = g * 4 + r;
                float val = s4[ktg][r] * l_[r];
                __builtin_nontemporal_store(val,
                    ap + (size_t)q * SEQ + ct * 128 + col);
                unsigned short hh = f2bf(val);
                int sch = chh ^ q;
                PTh[q * 128 + sch * 8 + (c & 7)] = hh;
                PTl[q * 128 + sch * 8 + (c & 7)] = f2bf(val - bf2f(hh));
            }
        }
        __syncthreads();
        // PV: A = P^T frags from LDS, B = V^T frags direct from global
#pragma unroll
        for (int ks = 0; ks < 4; ++ks) {
            const size_t vo = (size_t)ct * 128 + ks * 32;
            s16x8 Vh = *(const s16x8*)(Vbh + vo);
            s16x8 Vl = *(const s16x8*)(Vbl + vo);
            const int sch = (ks * 4 + g) ^ c;
            s16x8 Pa_h = *(const s16x8*)&PTh[c * 128 + sch * 8];
            s16x8 Pa_l = *(const s16x8*)&PTl[c * 128 + sch * 8];
            ctx = __builtin_amdgcn_mfma_f32_16x16x32_bf16(Pa_h, Vh, ctx, 0, 0, 0);
            ctx = __builtin_amdgcn_mfma_f32_16x16x32_bf16(Pa_h, Vl, ctx, 0, 0, 0);
            ctx = __builtin_amdgcn_mfma_f32_16x16x32_bf16(Pa_l, Vh, ctx, 0, 0, 0);
        }
    }

    // ---- epilogue: ctx -> chi/clo (merged (b,s,h*d), bf16 hi/lo) ----
    {
        int b = bh >> 4, h = bh & 15;
#pragma unroll
        for (int r = 0; r < 4; ++r) {
            int qrow = qt * 16 + g * 4 + r;
            float v = ctx[r];
            unsigned short hh = f2bf(v);
            size_t a = (((size_t)(b * SEQ + qrow)) << 10) + h * HD + w * 16 + c;
            chi[a] = hh;
            clo[a] = f2bf(v - bf2f(hh));
        }
    }
}

extern "C" void kernel_launch(void* const* d_in, const int* in_sizes, int n_in,
                              void* d_out, int out_size, void* d_ws, size_t ws_size,
                              hipStream_t stream) {
    const float* x  = (const float*)d_in[0];
    const float* wq = (const float*)d_in[1];
    const float* bq = (const float*)d_in[2];
    const float* wk = (const float*)d_in[3];
    const float* bk = (const float*)d_in[4];
    const float* wv = (const float*)d_in[5];
    const float* bv = (const float*)d_in[6];
    const float* wo = (const float*)d_in[7];
    const float* bo = (const float*)d_in[8];

    float* out      = (float*)d_out;
    float* attn_out = out + (size_t)BATCH * SEQ * EMB;

    const size_t MK = (size_t)MTOT * 1024;
    unsigned short* ws16 = (unsigned short*)d_ws;
    unsigned short* xhi  = ws16;             // reused as chi after qkv
    unsigned short* xlo  = xhi + MK;         // reused as clo
    unsigned short* whi  = xlo + MK;
    unsigned short* wlo  = whi + MK;
    unsigned short* qhi  = wlo + MK;
    unsigned short* qlo  = qhi + MK;
    unsigned short* khi  = qlo + MK;
    unsigned short* klo  = khi + MK;
    unsigned short* vthi = klo + MK;
    unsigned short* vtlo = vthi + MK;
    unsigned short* chi  = xhi;
    unsigned short* clo  = xlo;

    convert_x<<<MTOT, 256, 0, stream>>>(x, xhi, xlo);
    convert_w4<<<4096, 256, 0, stream>>>(wq, wk, wv, wo, whi, wlo);

    qkv_mfma<<<dim3(EMB / BN, MTOT / BM, 3), 256, 0, stream>>>(
        xhi, xlo, whi, wlo, bq, bk, bv, qhi, qlo, khi, klo, vthi, vtlo);

    attn_kernel<<<dim3(SEQ / 16, BATCH * HEADS), 256, 0, stream>>>(
        qhi, qlo, khi, klo, vthi, vtlo, attn_out, chi, clo);

    oproj_mfma<<<dim3(EMB / BN, MTOT / BM), 256, 0, stream>>>(
        chi, clo, whi, wlo, bo, out);
}

// Round 8
// 282.838 us; speedup vs baseline: 1.4169x; 1.4169x over previous
//
#include <hip/hip_runtime.h>
#include <math.h>

#define BATCH 4
#define SEQ   1024
#define EMB   1024
#define HEADS 16
#define HD    64
#define MTOT  (BATCH*SEQ)   // 4096

typedef float f32x4 __attribute__((ext_vector_type(4)));
typedef short s16x8 __attribute__((ext_vector_type(8)));

// ---- bf16 hi/lo split helpers (RNE) ---------------------------------------
__device__ __forceinline__ unsigned short f2bf(float f) {
    unsigned u = __float_as_uint(f);
    unsigned r = u + 0x7fffu + ((u >> 16) & 1u);
    return (unsigned short)(r >> 16);
}
__device__ __forceinline__ float bf2f(unsigned short h) {
    return __uint_as_float(((unsigned)h) << 16);
}

// ---- conversion kernels ---------------------------------------------------
__global__ __launch_bounds__(256) void convert_x(
    const float* __restrict__ in, unsigned short* __restrict__ hi,
    unsigned short* __restrict__ lo)
{
    size_t base = ((size_t)blockIdx.x << 10) + (threadIdx.x << 2);
    float4 v = *(const float4*)(in + base);
    ushort4 h, l;
    h.x = f2bf(v.x); l.x = f2bf(v.x - bf2f(h.x));
    h.y = f2bf(v.y); l.y = f2bf(v.y - bf2f(h.y));
    h.z = f2bf(v.z); l.z = f2bf(v.z - bf2f(h.z));
    h.w = f2bf(v.w); l.w = f2bf(v.w - bf2f(h.w));
    *(ushort4*)(hi + base) = h;
    *(ushort4*)(lo + base) = l;
}

__global__ __launch_bounds__(256) void convert_w4(
    const float* __restrict__ wq, const float* __restrict__ wk,
    const float* __restrict__ wv, const float* __restrict__ wo,
    unsigned short* __restrict__ hi, unsigned short* __restrict__ lo)
{
    int mi = blockIdx.x >> 10;
    int r  = blockIdx.x & 1023;
    const float* in = (mi == 0) ? wq : (mi == 1) ? wk : (mi == 2) ? wv : wo;
    size_t ib = ((size_t)r << 10) + (threadIdx.x << 2);
    size_t ob = ((size_t)mi << 20) + ib;
    float4 v = *(const float4*)(in + ib);
    ushort4 h, l;
    h.x = f2bf(v.x); l.x = f2bf(v.x - bf2f(h.x));
    h.y = f2bf(v.y); l.y = f2bf(v.y - bf2f(h.y));
    h.z = f2bf(v.z); l.z = f2bf(v.z - bf2f(h.z));
    h.w = f2bf(v.w); l.w = f2bf(v.w - bf2f(h.w));
    *(ushort4*)(hi + ob) = h;
    *(ushort4*)(lo + ob) = l;
}

// ---- split-bf16 MFMA GEMM tile (unchanged) --------------------------------
#define BM  128
#define BN  128
#define BKS 64
#define LDT 72

__device__ __forceinline__ void mfma_gemm_tile(
    const unsigned short* __restrict__ Ahi, const unsigned short* __restrict__ Alo,
    const unsigned short* __restrict__ Bhi, const unsigned short* __restrict__ Blo,
    int m0, int n0, f32x4 acc[4][4])
{
    __shared__ unsigned short As[BM * LDT];
    __shared__ unsigned short Bs[BM * LDT];
    const int tid  = threadIdx.x;
    const int lane = tid & 63;
    const int w    = tid >> 6;
    const int wr   = w >> 1, wc = w & 1;
    const int fr   = lane & 15;
    const int kb   = lane >> 4;

#pragma unroll
    for (int i = 0; i < 4; ++i)
#pragma unroll
        for (int j = 0; j < 4; ++j) acc[i][j] = (f32x4){0.f, 0.f, 0.f, 0.f};

    s16x8 ra[4], rb[4];
#define LOAD_STEP(KT)                                                          \
    {                                                                          \
        int seg = (KT) >> 4;                                                   \
        int k0  = ((KT) & 15) * BKS;                                           \
        const unsigned short* Ap = (seg < 2) ? Ahi : Alo;                      \
        const unsigned short* Bp = (seg == 1) ? Blo : Bhi;                     \
        _Pragma("unroll")                                                      \
        for (int i = 0; i < 4; ++i) {                                          \
            int c = tid + (i << 8);                                            \
            int row = c >> 3, cc = (c & 7) << 3;                               \
            ra[i] = *(const s16x8*)(Ap + ((size_t)(m0 + row) << 10) + k0 + cc);\
            rb[i] = *(const s16x8*)(Bp + ((size_t)(n0 + row) << 10) + k0 + cc);\
        }                                                                      \
    }

    LOAD_STEP(0);
    for (int kt = 0; kt < 48; ++kt) {
        __syncthreads();
#pragma unroll
        for (int i = 0; i < 4; ++i) {
            int c = tid + (i << 8);
            int row = c >> 3, cc = (c & 7) << 3;
            *(s16x8*)&As[row * LDT + cc] = ra[i];
            *(s16x8*)&Bs[row * LDT + cc] = rb[i];
        }
        if (kt + 1 < 48) LOAD_STEP(kt + 1);
        __syncthreads();
#pragma unroll
        for (int kc = 0; kc < 2; ++kc) {
            s16x8 aF[4], bF[4];
#pragma unroll
            for (int i = 0; i < 4; ++i)
                aF[i] = *(const s16x8*)&As[(wr * 64 + i * 16 + fr) * LDT + kc * 32 + kb * 8];
#pragma unroll
            for (int j = 0; j < 4; ++j)
                bF[j] = *(const s16x8*)&Bs[(wc * 64 + j * 16 + fr) * LDT + kc * 32 + kb * 8];
#pragma unroll
            for (int i = 0; i < 4; ++i)
#pragma unroll
                for (int j = 0; j < 4; ++j)
                    acc[i][j] = __builtin_amdgcn_mfma_f32_16x16x32_bf16(
                        aF[i], bF[j], acc[i][j], 0, 0, 0);
        }
    }
#undef LOAD_STEP
}

// QKV: writes Q,K as bf16 hi/lo (b,h,s,d); V transposed hi/lo (b,h,d,s).
__global__ __launch_bounds__(256, 2) void qkv_mfma(
    const unsigned short* __restrict__ xhi, const unsigned short* __restrict__ xlo,
    const unsigned short* __restrict__ whi, const unsigned short* __restrict__ wlo,
    const float* __restrict__ bq, const float* __restrict__ bk,
    const float* __restrict__ bv,
    unsigned short* __restrict__ qhi, unsigned short* __restrict__ qlo,
    unsigned short* __restrict__ khi, unsigned short* __restrict__ klo,
    unsigned short* __restrict__ vthi, unsigned short* __restrict__ vtlo)
{
    const int z = blockIdx.z;
    const unsigned short* Bh = whi + ((size_t)z << 20);
    const unsigned short* Bl = wlo + ((size_t)z << 20);
    const float* bias = (z == 0) ? bq : (z == 1) ? bk : bv;
    const int m0 = blockIdx.y * BM, n0 = blockIdx.x * BN;
    f32x4 acc[4][4];
    mfma_gemm_tile(xhi, xlo, Bh, Bl, m0, n0, acc);

    const int lane = threadIdx.x & 63;
    const int w    = threadIdx.x >> 6;
    const int wr   = w >> 1, wc = w & 1;
    const int fr   = lane & 15;
    const int rg   = lane >> 4;
#pragma unroll
    for (int i = 0; i < 4; ++i)
#pragma unroll
        for (int j = 0; j < 4; ++j) {
            int n = n0 + wc * 64 + j * 16 + fr;
            int h = n >> 6, d = n & 63;
            float bv_ = bias[n];
            int m_base = m0 + wr * 64 + i * 16 + rg * 4;
            int b = m_base >> 10, s0 = m_base & 1023;
            if (z < 2) {
                unsigned short* ph = (z == 0) ? qhi : khi;
                unsigned short* pl = (z == 0) ? qlo : klo;
#pragma unroll
                for (int r = 0; r < 4; ++r) {
                    float v = acc[i][j][r] + bv_;
                    unsigned short hh = f2bf(v);
                    size_t a = ((size_t)((b * HEADS + h) * SEQ + s0 + r)) * HD + d;
                    ph[a] = hh;
                    pl[a] = f2bf(v - bf2f(hh));
                }
            } else {
                ushort4 h4, l4;
                float v0 = acc[i][j][0] + bv_;
                float v1 = acc[i][j][1] + bv_;
                float v2 = acc[i][j][2] + bv_;
                float v3 = acc[i][j][3] + bv_;
                h4.x = f2bf(v0); l4.x = f2bf(v0 - bf2f(h4.x));
                h4.y = f2bf(v1); l4.y = f2bf(v1 - bf2f(h4.y));
                h4.z = f2bf(v2); l4.z = f2bf(v2 - bf2f(h4.z));
                h4.w = f2bf(v3); l4.w = f2bf(v3 - bf2f(h4.w));
                size_t a = ((size_t)((b * HEADS + h) * HD + d)) * SEQ + s0;
                *(ushort4*)(vthi + a) = h4;
                *(ushort4*)(vtlo + a) = l4;
            }
        }
}

// OPROJ (unchanged)
__global__ __launch_bounds__(256, 2) void oproj_mfma(
    const unsigned short* __restrict__ chi, const unsigned short* __restrict__ clo,
    const unsigned short* __restrict__ whi, const unsigned short* __restrict__ wlo,
    const float* __restrict__ bo, float* __restrict__ out)
{
    const unsigned short* Bh = whi + ((size_t)3 << 20);
    const unsigned short* Bl = wlo + ((size_t)3 << 20);
    const int m0 = blockIdx.y * BM, n0 = blockIdx.x * BN;
    f32x4 acc[4][4];
    mfma_gemm_tile(chi, clo, Bh, Bl, m0, n0, acc);

    const int lane = threadIdx.x & 63;
    const int w    = threadIdx.x >> 6;
    const int wr   = w >> 1, wc = w & 1;
    const int fr   = lane & 15;
    const int rg   = lane >> 4;
#pragma unroll
    for (int i = 0; i < 4; ++i)
#pragma unroll
        for (int j = 0; j < 4; ++j) {
            int n = n0 + wc * 64 + j * 16 + fr;
            float bv_ = bo[n];
#pragma unroll
            for (int r = 0; r < 4; ++r) {
                int m = m0 + wr * 64 + i * 16 + rg * 4 + r;
                out[(size_t)m * EMB + n] = acc[i][j][r] + bv_;
            }
        }
}

// ---------------- attention: round-6 structure, 32 q-rows / 8 waves --------
// Waves 0-3 = q-subtile group 0, waves 4-7 = group 1; both groups share the
// LDS-staged K/V tiles (staging traffic halved vs 16-row blocks). Scores
// stay 16 f32x4 per thread. LDS: phase1 KT hi[0,4096) lo[4096,8192) ushorts;
// phase3 VT hi[0,8192) lo[8192,16384), PT hi[16384,20480) lo[20480,24576).
// XOR-swizzle on all tiles (T2).
__global__ __launch_bounds__(512, 4) void attn_kernel(
    const unsigned short* __restrict__ qhi, const unsigned short* __restrict__ qlo,
    const unsigned short* __restrict__ khi, const unsigned short* __restrict__ klo,
    const unsigned short* __restrict__ vthi, const unsigned short* __restrict__ vtlo,
    float* __restrict__ attn,
    unsigned short* __restrict__ chi, unsigned short* __restrict__ clo)
{
    __shared__ unsigned short SM[24576];   // 48 KB
    __shared__ float RMAX[8][16];
    __shared__ float RSUM[8][16];

    const int lid = blockIdx.y * gridDim.x + blockIdx.x;  // 0..2047
    const int xs  = lid & 7;
    const int jj  = lid >> 3;            // 0..255
    const int bh  = xs * 8 + (jj >> 5);  // 0..63 (XCD-pinned heads)
    const int qt  = jj & 31;             // 0..31 (32-row q tile)

    const int tid  = threadIdx.x;
    const int w    = tid >> 6;           // 0..7
    const int grp  = w >> 2;             // q-subtile group
    const int wg   = w & 3;              // wave within group
    const int lane = tid & 63;
    const int c    = lane & 15;
    const int g    = lane >> 4;

    const size_t bhS = (size_t)bh * SEQ;

    // Q A-frags: lane holds q-row = qt*32 + grp*16 + c
    s16x8 Qh[2], Ql[2];
    {
        size_t qb = (bhS + qt * 32 + grp * 16 + c) * HD + g * 8;
        Qh[0] = *(const s16x8*)(qhi + qb);
        Qh[1] = *(const s16x8*)(qhi + qb + 32);
        Ql[0] = *(const s16x8*)(qlo + qb);
        Ql[1] = *(const s16x8*)(qlo + qb + 32);
    }

    f32x4 s4[16];
#pragma unroll
    for (int kt = 0; kt < 16; ++kt) s4[kt] = (f32x4){0.f, 0.f, 0.f, 0.f};

    // ---- phase 1: QK^T, K staged in LDS (one shot: 512 thr = full tile) ---
    const int srow = tid >> 3;           // 0..63
    const int sch  = tid & 7;
    const int sswz = sch ^ (srow & 7);
#pragma unroll
    for (int kt = 0; kt < 16; ++kt) {
        size_t ga = (bhS + kt * 64 + srow) * HD + sch * 8;
        s16x8 sh = *(const s16x8*)(khi + ga);
        s16x8 sl = *(const s16x8*)(klo + ga);
        __syncthreads();   // prev tile frag reads done
        *(s16x8*)&SM[srow * 64 + sswz * 8]        = sh;
        *(s16x8*)&SM[4096 + srow * 64 + sswz * 8] = sl;
        __syncthreads();
        const int krow = wg * 16 + c;
        const int cs   = c & 7;
        s16x8 Bh0 = *(const s16x8*)&SM[krow * 64 + ((0 + g) ^ cs) * 8];
        s16x8 Bh1 = *(const s16x8*)&SM[krow * 64 + ((4 + g) ^ cs) * 8];
        s16x8 Bl0 = *(const s16x8*)&SM[4096 + krow * 64 + ((0 + g) ^ cs) * 8];
        s16x8 Bl1 = *(const s16x8*)&SM[4096 + krow * 64 + ((4 + g) ^ cs) * 8];
        s4[kt] = __builtin_amdgcn_mfma_f32_16x16x32_bf16(Qh[0], Bh0, s4[kt], 0, 0, 0);
        s4[kt] = __builtin_amdgcn_mfma_f32_16x16x32_bf16(Qh[1], Bh1, s4[kt], 0, 0, 0);
        s4[kt] = __builtin_amdgcn_mfma_f32_16x16x32_bf16(Qh[0], Bl0, s4[kt], 0, 0, 0);
        s4[kt] = __builtin_amdgcn_mfma_f32_16x16x32_bf16(Qh[1], Bl1, s4[kt], 0, 0, 0);
        s4[kt] = __builtin_amdgcn_mfma_f32_16x16x32_bf16(Ql[0], Bh0, s4[kt], 0, 0, 0);
        s4[kt] = __builtin_amdgcn_mfma_f32_16x16x32_bf16(Ql[1], Bh1, s4[kt], 0, 0, 0);
    }

    // ---- softmax (per group; lane holds q-rows g*4+r of its group) ----
    float m_[4], l_[4];
#pragma unroll
    for (int r = 0; r < 4; ++r) {
        float mm = -1e30f;
#pragma unroll
        for (int kt = 0; kt < 16; ++kt) {
            s4[kt][r] *= 0.125f;
            mm = fmaxf(mm, s4[kt][r]);
        }
        m_[r] = mm;
    }
#pragma unroll
    for (int off = 1; off < 16; off <<= 1)
#pragma unroll
        for (int r = 0; r < 4; ++r) m_[r] = fmaxf(m_[r], __shfl_xor(m_[r], off));
    if (c == 0) {
#pragma unroll
        for (int r = 0; r < 4; ++r) RMAX[w][g * 4 + r] = m_[r];
    }
    __syncthreads();
#pragma unroll
    for (int r = 0; r < 4; ++r)
        m_[r] = fmaxf(fmaxf(RMAX[grp * 4 + 0][g * 4 + r], RMAX[grp * 4 + 1][g * 4 + r]),
                      fmaxf(RMAX[grp * 4 + 2][g * 4 + r], RMAX[grp * 4 + 3][g * 4 + r]));
#pragma unroll
    for (int r = 0; r < 4; ++r) {
        float ss = 0.f;
#pragma unroll
        for (int kt = 0; kt < 16; ++kt) {
            float p = __expf(s4[kt][r] - m_[r]);
            s4[kt][r] = p;
            ss += p;
        }
        l_[r] = ss;
    }
#pragma unroll
    for (int off = 1; off < 16; off <<= 1)
#pragma unroll
        for (int r = 0; r < 4; ++r) l_[r] += __shfl_xor(l_[r], off);
    if (c == 0) {
#pragma unroll
        for (int r = 0; r < 4; ++r) RSUM[w][g * 4 + r] = l_[r];
    }
    __syncthreads();
#pragma unroll
    for (int r = 0; r < 4; ++r)
        l_[r] = 1.f / (RSUM[grp * 4 + 0][g * 4 + r] + RSUM[grp * 4 + 1][g * 4 + r] +
                       RSUM[grp * 4 + 2][g * 4 + r] + RSUM[grp * 4 + 3][g * 4 + r]);

    // ---- phase 3: attn write + PV (8 chunks of 128 k) ----
    f32x4 ctx = (f32x4){0.f, 0.f, 0.f, 0.f};
    float* ap = attn + (bhS + qt * 32) * SEQ;
    const int vrow0 = tid >> 4;          // 0..31 (t adds 32)
    const int vch   = tid & 15;

#pragma unroll
    for (int ct = 0; ct < 8; ++ct) {
        s16x8 vh[2], vl[2];
#pragma unroll
        for (int t = 0; t < 2; ++t) {
            int drow = vrow0 + t * 32;
            size_t ga = ((size_t)bh * HD + drow) * SEQ + ct * 128 + vch * 8;
            vh[t] = *(const s16x8*)(vthi + ga);
            vl[t] = *(const s16x8*)(vtlo + ga);
        }
        __syncthreads();   // prev chunk frag reads (or phase-1 reads) done
#pragma unroll
        for (int t = 0; t < 2; ++t) {
            int drow = vrow0 + t * 32;
            int swz = vch ^ (drow & 7);
            *(s16x8*)&SM[drow * 128 + swz * 8]        = vh[t];
            *(s16x8*)&SM[8192 + drow * 128 + swz * 8] = vl[t];
        }
        // normalized P -> attn (nontemporal) + PT hi/lo (swizzled)
#pragma unroll
        for (int kt2 = 0; kt2 < 2; ++kt2) {
            const int ktg = ct * 2 + kt2;
            const int col = kt2 * 64 + wg * 16 + c;
            const int chh = col >> 3;
#pragma unroll
            for (int r = 0; r < 4; ++r) {
                const int q = g * 4 + r;
                float val = s4[ktg][r] * l_[r];
                __builtin_nontemporal_store(val,
                    ap + (size_t)(grp * 16 + q) * SEQ + ct * 128 + col);
                unsigned short hh = f2bf(val);
                int schP = chh ^ q;
                SM[16384 + (grp * 16 + q) * 128 + schP * 8 + (c & 7)] = hh;
                SM[20480 + (grp * 16 + q) * 128 + schP * 8 + (c & 7)] =
                    f2bf(val - bf2f(hh));
            }
        }
        __syncthreads();
        // PV: A = P frags (own group's PT), B = V^T frags (shared)
        const int drow = wg * 16 + c;
        const int ds7  = drow & 7;
#pragma unroll
        for (int ks = 0; ks < 4; ++ks) {
            s16x8 Vh = *(const s16x8*)&SM[drow * 128 + ((ks * 4 + g) ^ ds7) * 8];
            s16x8 Vl = *(const s16x8*)&SM[8192 + drow * 128 + ((ks * 4 + g) ^ ds7) * 8];
            const int pch = (ks * 4 + g) ^ c;
            s16x8 Pa_h = *(const s16x8*)&SM[16384 + (grp * 16 + c) * 128 + pch * 8];
            s16x8 Pa_l = *(const s16x8*)&SM[20480 + (grp * 16 + c) * 128 + pch * 8];
            ctx = __builtin_amdgcn_mfma_f32_16x16x32_bf16(Pa_h, Vh, ctx, 0, 0, 0);
            ctx = __builtin_amdgcn_mfma_f32_16x16x32_bf16(Pa_h, Vl, ctx, 0, 0, 0);
            ctx = __builtin_amdgcn_mfma_f32_16x16x32_bf16(Pa_l, Vh, ctx, 0, 0, 0);
        }
    }

    // ---- epilogue: ctx -> chi/clo (merged (b,s,h*d), bf16 hi/lo) ----
    {
        int b = bh >> 4, h = bh & 15;
#pragma unroll
        for (int r = 0; r < 4; ++r) {
            int qrow = qt * 32 + grp * 16 + g * 4 + r;
            float v = ctx[r];
            unsigned short hh = f2bf(v);
            size_t a = (((size_t)(b * SEQ + qrow)) << 10) + h * HD + wg * 16 + c;
            chi[a] = hh;
            clo[a] = f2bf(v - bf2f(hh));
        }
    }
}

extern "C" void kernel_launch(void* const* d_in, const int* in_sizes, int n_in,
                              void* d_out, int out_size, void* d_ws, size_t ws_size,
                              hipStream_t stream) {
    const float* x  = (const float*)d_in[0];
    const float* wq = (const float*)d_in[1];
    const float* bq = (const float*)d_in[2];
    const float* wk = (const float*)d_in[3];
    const float* bk = (const float*)d_in[4];
    const float* wv = (const float*)d_in[5];
    const float* bv = (const float*)d_in[6];
    const float* wo = (const float*)d_in[7];
    const float* bo = (const float*)d_in[8];

    float* out      = (float*)d_out;
    float* attn_out = out + (size_t)BATCH * SEQ * EMB;

    const size_t MK = (size_t)MTOT * 1024;
    unsigned short* ws16 = (unsigned short*)d_ws;
    unsigned short* xhi  = ws16;             // reused as chi after qkv
    unsigned short* xlo  = xhi + MK;         // reused as clo
    unsigned short* whi  = xlo + MK;
    unsigned short* wlo  = whi + MK;
    unsigned short* qhi  = wlo + MK;
    unsigned short* qlo  = qhi + MK;
    unsigned short* khi  = qlo + MK;
    unsigned short* klo  = khi + MK;
    unsigned short* vthi = klo + MK;
    unsigned short* vtlo = vthi + MK;
    unsigned short* chi  = xhi;
    unsigned short* clo  = xlo;

    convert_x<<<MTOT, 256, 0, stream>>>(x, xhi, xlo);
    convert_w4<<<4096, 256, 0, stream>>>(wq, wk, wv, wo, whi, wlo);

    qkv_mfma<<<dim3(EMB / BN, MTOT / BM, 3), 256, 0, stream>>>(
        xhi, xlo, whi, wlo, bq, bk, bv, qhi, qlo, khi, klo, vthi, vtlo);

    attn_kernel<<<dim3(SEQ / 32, BATCH * HEADS), 512, 0, stream>>>(
        qhi, qlo, khi, klo, vthi, vtlo, attn_out, chi, clo);

    oproj_mfma<<<dim3(EMB / BN, MTOT / BM), 256, 0, stream>>>(
        chi, clo, whi, wlo, bo, out);
}

// Round 9
// 160.473 us; speedup vs baseline: 2.4974x; 1.7625x over previous
//
#include <hip/hip_runtime.h>
#include <math.h>

#define BATCH 4
#define SEQ   1024
#define EMB   1024
#define HEADS 16
#define HD    64
#define MTOT  (BATCH*SEQ)   // 4096

typedef float    f32x4 __attribute__((ext_vector_type(4)));
typedef _Float16 f16;
typedef _Float16 f16x4 __attribute__((ext_vector_type(4)));
typedef _Float16 f16x8 __attribute__((ext_vector_type(8)));

// ---- conversion: x (4096 rows) + 4 weights (4096 rows) -> fp16 ------------
__global__ __launch_bounds__(256) void convert_all(
    const float* __restrict__ x,
    const float* __restrict__ wq, const float* __restrict__ wk,
    const float* __restrict__ wv, const float* __restrict__ wo,
    f16* __restrict__ xh, f16* __restrict__ wh)
{
    const int bid = blockIdx.x;          // 0..8191
    const float* src;
    f16* dst;
    if (bid < 4096) {
        src = x + ((size_t)bid << 10);
        dst = xh + ((size_t)bid << 10);
    } else {
        int t  = bid - 4096;
        int mi = t >> 10, r = t & 1023;
        const float* in = (mi == 0) ? wq : (mi == 1) ? wk : (mi == 2) ? wv : wo;
        src = in + ((size_t)r << 10);
        dst = wh + ((size_t)mi << 20) + ((size_t)r << 10);
    }
    int o = threadIdx.x << 2;
    float4 v = *(const float4*)(src + o);
    f16x4 h;
    h.x = (f16)v.x; h.y = (f16)v.y; h.z = (f16)v.z; h.w = (f16)v.w;
    *(f16x4*)(dst + o) = h;
}

// ---- fp16 single-pass MFMA GEMM tile: C = A @ W^T -------------------------
#define BM  128
#define BN  128
#define LDT 72   // f16 elems per padded LDS row

__device__ __forceinline__ void mfma_gemm_tile(
    const f16* __restrict__ A, const f16* __restrict__ B,
    int m0, int n0, f32x4 acc[4][4])
{
    __shared__ f16 As[BM * LDT];
    __shared__ f16 Bs[BM * LDT];
    const int tid  = threadIdx.x;
    const int lane = tid & 63;
    const int w    = tid >> 6;
    const int wr   = w >> 1, wc = w & 1;
    const int fr   = lane & 15;
    const int kb   = lane >> 4;

#pragma unroll
    for (int i = 0; i < 4; ++i)
#pragma unroll
        for (int j = 0; j < 4; ++j) acc[i][j] = (f32x4){0.f, 0.f, 0.f, 0.f};

    f16x8 ra[4], rb[4];
#define LOAD_STEP(KT)                                                          \
    {                                                                          \
        int k0 = (KT) * 64;                                                    \
        _Pragma("unroll")                                                      \
        for (int i = 0; i < 4; ++i) {                                          \
            int c = tid + (i << 8);                                            \
            int row = c >> 3, cc = (c & 7) << 3;                               \
            ra[i] = *(const f16x8*)(A + ((size_t)(m0 + row) << 10) + k0 + cc); \
            rb[i] = *(const f16x8*)(B + ((size_t)(n0 + row) << 10) + k0 + cc); \
        }                                                                      \
    }

    LOAD_STEP(0);
    for (int kt = 0; kt < 16; ++kt) {
        __syncthreads();
#pragma unroll
        for (int i = 0; i < 4; ++i) {
            int c = tid + (i << 8);
            int row = c >> 3, cc = (c & 7) << 3;
            *(f16x8*)&As[row * LDT + cc] = ra[i];
            *(f16x8*)&Bs[row * LDT + cc] = rb[i];
        }
        if (kt + 1 < 16) LOAD_STEP(kt + 1);
        __syncthreads();
#pragma unroll
        for (int kc = 0; kc < 2; ++kc) {
            f16x8 aF[4], bF[4];
#pragma unroll
            for (int i = 0; i < 4; ++i)
                aF[i] = *(const f16x8*)&As[(wr * 64 + i * 16 + fr) * LDT + kc * 32 + kb * 8];
#pragma unroll
            for (int j = 0; j < 4; ++j)
                bF[j] = *(const f16x8*)&Bs[(wc * 64 + j * 16 + fr) * LDT + kc * 32 + kb * 8];
#pragma unroll
            for (int i = 0; i < 4; ++i)
#pragma unroll
                for (int j = 0; j < 4; ++j)
                    acc[i][j] = __builtin_amdgcn_mfma_f32_16x16x32_f16(
                        aF[i], bF[j], acc[i][j], 0, 0, 0);
        }
    }
#undef LOAD_STEP
}

// QKV: writes Q,K fp16 (b,h,s,d); V transposed fp16 (b,h,d,s).
__global__ __launch_bounds__(256, 2) void qkv_mfma(
    const f16* __restrict__ xh, const f16* __restrict__ wh,
    const float* __restrict__ bq, const float* __restrict__ bk,
    const float* __restrict__ bv,
    f16* __restrict__ qh, f16* __restrict__ kh, f16* __restrict__ vth)
{
    const int z = blockIdx.z;
    const f16* Bm = wh + ((size_t)z << 20);
    const float* bias = (z == 0) ? bq : (z == 1) ? bk : bv;
    const int m0 = blockIdx.y * BM, n0 = blockIdx.x * BN;
    f32x4 acc[4][4];
    mfma_gemm_tile(xh, Bm, m0, n0, acc);

    const int lane = threadIdx.x & 63;
    const int w    = threadIdx.x >> 6;
    const int wr   = w >> 1, wc = w & 1;
    const int fr   = lane & 15;
    const int rg   = lane >> 4;
#pragma unroll
    for (int i = 0; i < 4; ++i)
#pragma unroll
        for (int j = 0; j < 4; ++j) {
            int n = n0 + wc * 64 + j * 16 + fr;
            int h = n >> 6, d = n & 63;
            float bv_ = bias[n];
            int m_base = m0 + wr * 64 + i * 16 + rg * 4;
            int b = m_base >> 10, s0 = m_base & 1023;
            if (z < 2) {
                f16* p = (z == 0) ? qh : kh;
#pragma unroll
                for (int r = 0; r < 4; ++r) {
                    float v = acc[i][j][r] + bv_;
                    p[((size_t)((b * HEADS + h) * SEQ + s0 + r)) * HD + d] = (f16)v;
                }
            } else {
                f16x4 h4;
                h4.x = (f16)(acc[i][j][0] + bv_);
                h4.y = (f16)(acc[i][j][1] + bv_);
                h4.z = (f16)(acc[i][j][2] + bv_);
                h4.w = (f16)(acc[i][j][3] + bv_);
                size_t a = ((size_t)((b * HEADS + h) * HD + d)) * SEQ + s0;
                *(f16x4*)(vth + a) = h4;
            }
        }
}

// OPROJ: ctx fp16 @ wo^T + bo -> out fp32
__global__ __launch_bounds__(256, 2) void oproj_mfma(
    const f16* __restrict__ ch, const f16* __restrict__ wh,
    const float* __restrict__ bo, float* __restrict__ out)
{
    const f16* Bm = wh + ((size_t)3 << 20);
    const int m0 = blockIdx.y * BM, n0 = blockIdx.x * BN;
    f32x4 acc[4][4];
    mfma_gemm_tile(ch, Bm, m0, n0, acc);

    const int lane = threadIdx.x & 63;
    const int w    = threadIdx.x >> 6;
    const int wr   = w >> 1, wc = w & 1;
    const int fr   = lane & 15;
    const int rg   = lane >> 4;
#pragma unroll
    for (int i = 0; i < 4; ++i)
#pragma unroll
        for (int j = 0; j < 4; ++j) {
            int n = n0 + wc * 64 + j * 16 + fr;
            float bv_ = bo[n];
#pragma unroll
            for (int r = 0; r < 4; ++r) {
                int m = m0 + wr * 64 + i * 16 + rg * 4 + r;
                out[(size_t)m * EMB + n] = acc[i][j][r] + bv_;
            }
        }
}

// ---------------- attention: fp16 single-pass MFMA, 32 q-rows / 8 waves ----
// Waves 0-3 = q-subtile 0, waves 4-7 = subtile 1, sharing staged K/V tiles.
// LDS (f16 elems): phase1 KT [0,4096); phase3 VT [0,8192), PT [8192,12288).
// XOR-swizzle chunk^=(row&7) on all tiles.
__global__ __launch_bounds__(512, 4) void attn_kernel(
    const f16* __restrict__ qh, const f16* __restrict__ kh,
    const f16* __restrict__ vth,
    float* __restrict__ attn, f16* __restrict__ ch)
{
    __shared__ f16 SM[12288];   // 24 KB
    __shared__ float RMAX[8][16];
    __shared__ float RSUM[8][16];

    const int lid = blockIdx.y * gridDim.x + blockIdx.x;  // 0..2047
    const int xs  = lid & 7;
    const int jj  = lid >> 3;
    const int bh  = xs * 8 + (jj >> 5);
    const int qt  = jj & 31;

    const int tid  = threadIdx.x;
    const int w    = tid >> 6;
    const int grp  = w >> 2;
    const int wg   = w & 3;
    const int lane = tid & 63;
    const int c    = lane & 15;
    const int g    = lane >> 4;

    const size_t bhS = (size_t)bh * SEQ;

    // Q A-frags: lane holds q-row = qt*32 + grp*16 + c
    f16x8 Q0, Q1;
    {
        size_t qb = (bhS + qt * 32 + grp * 16 + c) * HD + g * 8;
        Q0 = *(const f16x8*)(qh + qb);
        Q1 = *(const f16x8*)(qh + qb + 32);
    }

    f32x4 s4[16];
#pragma unroll
    for (int kt = 0; kt < 16; ++kt) s4[kt] = (f32x4){0.f, 0.f, 0.f, 0.f};

    // ---- phase 1: QK^T, K tile (64x64 f16) staged by all 512 threads ----
    const int srow = tid >> 3;           // 0..63
    const int sch  = tid & 7;
    const int sswz = sch ^ (srow & 7);
#pragma unroll
    for (int kt = 0; kt < 16; ++kt) {
        size_t ga = (bhS + kt * 64 + srow) * HD + sch * 8;
        f16x8 sh = *(const f16x8*)(kh + ga);
        __syncthreads();   // prev tile frag reads done
        *(f16x8*)&SM[srow * 64 + sswz * 8] = sh;
        __syncthreads();
        const int krow = wg * 16 + c;
        const int cs   = c & 7;
        f16x8 B0 = *(const f16x8*)&SM[krow * 64 + ((0 + g) ^ cs) * 8];
        f16x8 B1 = *(const f16x8*)&SM[krow * 64 + ((4 + g) ^ cs) * 8];
        s4[kt] = __builtin_amdgcn_mfma_f32_16x16x32_f16(Q0, B0, s4[kt], 0, 0, 0);
        s4[kt] = __builtin_amdgcn_mfma_f32_16x16x32_f16(Q1, B1, s4[kt], 0, 0, 0);
    }

    // ---- softmax (per 4-wave group) ----
    float m_[4], l_[4];
#pragma unroll
    for (int r = 0; r < 4; ++r) {
        float mm = -1e30f;
#pragma unroll
        for (int kt = 0; kt < 16; ++kt) {
            s4[kt][r] *= 0.125f;
            mm = fmaxf(mm, s4[kt][r]);
        }
        m_[r] = mm;
    }
#pragma unroll
    for (int off = 1; off < 16; off <<= 1)
#pragma unroll
        for (int r = 0; r < 4; ++r) m_[r] = fmaxf(m_[r], __shfl_xor(m_[r], off));
    if (c == 0) {
#pragma unroll
        for (int r = 0; r < 4; ++r) RMAX[w][g * 4 + r] = m_[r];
    }
    __syncthreads();
#pragma unroll
    for (int r = 0; r < 4; ++r)
        m_[r] = fmaxf(fmaxf(RMAX[grp * 4 + 0][g * 4 + r], RMAX[grp * 4 + 1][g * 4 + r]),
                      fmaxf(RMAX[grp * 4 + 2][g * 4 + r], RMAX[grp * 4 + 3][g * 4 + r]));
#pragma unroll
    for (int r = 0; r < 4; ++r) {
        float ss = 0.f;
#pragma unroll
        for (int kt = 0; kt < 16; ++kt) {
            float p = __expf(s4[kt][r] - m_[r]);
            s4[kt][r] = p;
            ss += p;
        }
        l_[r] = ss;
    }
#pragma unroll
    for (int off = 1; off < 16; off <<= 1)
#pragma unroll
        for (int r = 0; r < 4; ++r) l_[r] += __shfl_xor(l_[r], off);
    if (c == 0) {
#pragma unroll
        for (int r = 0; r < 4; ++r) RSUM[w][g * 4 + r] = l_[r];
    }
    __syncthreads();
#pragma unroll
    for (int r = 0; r < 4; ++r)
        l_[r] = 1.f / (RSUM[grp * 4 + 0][g * 4 + r] + RSUM[grp * 4 + 1][g * 4 + r] +
                       RSUM[grp * 4 + 2][g * 4 + r] + RSUM[grp * 4 + 3][g * 4 + r]);

    // ---- phase 3: attn write + PV (8 chunks of 128 k) ----
    f32x4 ctx = (f32x4){0.f, 0.f, 0.f, 0.f};
    float* ap = attn + (bhS + qt * 32) * SEQ;
    const int vrow0 = tid >> 4;          // 0..31 (t adds 32)
    const int vch   = tid & 15;

#pragma unroll
    for (int ct = 0; ct < 8; ++ct) {
        f16x8 vv[2];
#pragma unroll
        for (int t = 0; t < 2; ++t) {
            int drow = vrow0 + t * 32;
            size_t ga = ((size_t)bh * HD + drow) * SEQ + ct * 128 + vch * 8;
            vv[t] = *(const f16x8*)(vth + ga);
        }
        __syncthreads();   // prev chunk frag reads (or phase-1 reads) done
#pragma unroll
        for (int t = 0; t < 2; ++t) {
            int drow = vrow0 + t * 32;
            int swz = vch ^ (drow & 7);
            *(f16x8*)&SM[drow * 128 + swz * 8] = vv[t];
        }
        // normalized P -> attn (nontemporal f32) + PT fp16 (swizzled)
#pragma unroll
        for (int kt2 = 0; kt2 < 2; ++kt2) {
            const int ktg = ct * 2 + kt2;
            const int col = kt2 * 64 + wg * 16 + c;
            const int chh = col >> 3;
#pragma unroll
            for (int r = 0; r < 4; ++r) {
                const int q = g * 4 + r;
                float val = s4[ktg][r] * l_[r];
                __builtin_nontemporal_store(val,
                    ap + (size_t)(grp * 16 + q) * SEQ + ct * 128 + col);
                int schP = chh ^ q;
                SM[8192 + (grp * 16 + q) * 128 + schP * 8 + (c & 7)] = (f16)val;
            }
        }
        __syncthreads();
        // PV: A = P frags (own group), B = V^T frags (shared)
        const int drow = wg * 16 + c;
        const int ds7  = drow & 7;
#pragma unroll
        for (int ks = 0; ks < 4; ++ks) {
            f16x8 Vh = *(const f16x8*)&SM[drow * 128 + ((ks * 4 + g) ^ ds7) * 8];
            f16x8 Pa = *(const f16x8*)&SM[8192 + (grp * 16 + c) * 128 + (((ks * 4 + g) ^ c) & 15) * 8];
            ctx = __builtin_amdgcn_mfma_f32_16x16x32_f16(Pa, Vh, ctx, 0, 0, 0);
        }
    }

    // ---- epilogue: ctx -> ch (merged (b,s,h*d), fp16) ----
    {
        int b = bh >> 4, h = bh & 15;
#pragma unroll
        for (int r = 0; r < 4; ++r) {
            int qrow = qt * 32 + grp * 16 + g * 4 + r;
            size_t a = (((size_t)(b * SEQ + qrow)) << 10) + h * HD + wg * 16 + c;
            ch[a] = (f16)ctx[r];
        }
    }
}

extern "C" void kernel_launch(void* const* d_in, const int* in_sizes, int n_in,
                              void* d_out, int out_size, void* d_ws, size_t ws_size,
                              hipStream_t stream) {
    const float* x  = (const float*)d_in[0];
    const float* wq = (const float*)d_in[1];
    const float* bq = (const float*)d_in[2];
    const float* wk = (const float*)d_in[3];
    const float* bk = (const float*)d_in[4];
    const float* wv = (const float*)d_in[5];
    const float* bv = (const float*)d_in[6];
    const float* wo = (const float*)d_in[7];
    const float* bo = (const float*)d_in[8];

    float* out      = (float*)d_out;
    float* attn_out = out + (size_t)BATCH * SEQ * EMB;

    const size_t MK = (size_t)MTOT * 1024;
    f16* ws16 = (f16*)d_ws;
    f16* xh  = ws16;                     // reused as ch after qkv
    f16* wh  = xh + MK;                  // 4 planes of 1024x1024
    f16* qh  = wh + ((size_t)4 << 20);
    f16* kh  = qh + MK;
    f16* vth = kh + MK;
    f16* ch  = xh;

    convert_all<<<8192, 256, 0, stream>>>(x, wq, wk, wv, wo, xh, wh);

    qkv_mfma<<<dim3(EMB / BN, MTOT / BM, 3), 256, 0, stream>>>(
        xh, wh, bq, bk, bv, qh, kh, vth);

    attn_kernel<<<dim3(SEQ / 32, BATCH * HEADS), 512, 0, stream>>>(
        qh, kh, vth, attn_out, ch);

    oproj_mfma<<<dim3(EMB / BN, MTOT / BM), 256, 0, stream>>>(
        ch, wh, bo, out);
}

// Round 10
// 148.159 us; speedup vs baseline: 2.7050x; 1.0831x over previous
//
#include <hip/hip_runtime.h>
#include <math.h>

#define BATCH 4
#define SEQ   1024
#define EMB   1024
#define HEADS 16
#define HD    64
#define MTOT  (BATCH*SEQ)   // 4096

typedef float    f32x4 __attribute__((ext_vector_type(4)));
typedef float    vf4   __attribute__((ext_vector_type(4)));
typedef _Float16 f16;
typedef _Float16 f16x4 __attribute__((ext_vector_type(4)));
typedef _Float16 f16x8 __attribute__((ext_vector_type(8)));

// ---- conversion: x (4096 rows) + 4 weights (4096 rows) -> fp16 ------------
__global__ __launch_bounds__(256) void convert_all(
    const float* __restrict__ x,
    const float* __restrict__ wq, const float* __restrict__ wk,
    const float* __restrict__ wv, const float* __restrict__ wo,
    f16* __restrict__ xh, f16* __restrict__ wh)
{
    const int bid = blockIdx.x;          // 0..8191
    const float* src;
    f16* dst;
    if (bid < 4096) {
        src = x + ((size_t)bid << 10);
        dst = xh + ((size_t)bid << 10);
    } else {
        int t  = bid - 4096;
        int mi = t >> 10, r = t & 1023;
        const float* in = (mi == 0) ? wq : (mi == 1) ? wk : (mi == 2) ? wv : wo;
        src = in + ((size_t)r << 10);
        dst = wh + ((size_t)mi << 20) + ((size_t)r << 10);
    }
    int o = threadIdx.x << 2;
    float4 v = *(const float4*)(src + o);
    f16x4 h;
    h.x = (f16)v.x; h.y = (f16)v.y; h.z = (f16)v.z; h.w = (f16)v.w;
    *(f16x4*)(dst + o) = h;
}

// ---- fp16 single-pass MFMA GEMM tile: C = A @ W^T -------------------------
#define BM  128
#define BN  128
#define LDT 72   // f16 elems per padded LDS row

__device__ __forceinline__ void mfma_gemm_tile(
    const f16* __restrict__ A, const f16* __restrict__ B,
    int m0, int n0, f32x4 acc[4][4])
{
    __shared__ f16 As[BM * LDT];
    __shared__ f16 Bs[BM * LDT];
    const int tid  = threadIdx.x;
    const int lane = tid & 63;
    const int w    = tid >> 6;
    const int wr   = w >> 1, wc = w & 1;
    const int fr   = lane & 15;
    const int kb   = lane >> 4;

#pragma unroll
    for (int i = 0; i < 4; ++i)
#pragma unroll
        for (int j = 0; j < 4; ++j) acc[i][j] = (f32x4){0.f, 0.f, 0.f, 0.f};

    f16x8 ra[4], rb[4];
#define LOAD_STEP(KT)                                                          \
    {                                                                          \
        int k0 = (KT) * 64;                                                    \
        _Pragma("unroll")                                                      \
        for (int i = 0; i < 4; ++i) {                                          \
            int c = tid + (i << 8);                                            \
            int row = c >> 3, cc = (c & 7) << 3;                               \
            ra[i] = *(const f16x8*)(A + ((size_t)(m0 + row) << 10) + k0 + cc); \
            rb[i] = *(const f16x8*)(B + ((size_t)(n0 + row) << 10) + k0 + cc); \
        }                                                                      \
    }

    LOAD_STEP(0);
    for (int kt = 0; kt < 16; ++kt) {
        __syncthreads();
#pragma unroll
        for (int i = 0; i < 4; ++i) {
            int c = tid + (i << 8);
            int row = c >> 3, cc = (c & 7) << 3;
            *(f16x8*)&As[row * LDT + cc] = ra[i];
            *(f16x8*)&Bs[row * LDT + cc] = rb[i];
        }
        if (kt + 1 < 16) LOAD_STEP(kt + 1);
        __syncthreads();
#pragma unroll
        for (int kc = 0; kc < 2; ++kc) {
            f16x8 aF[4], bF[4];
#pragma unroll
            for (int i = 0; i < 4; ++i)
                aF[i] = *(const f16x8*)&As[(wr * 64 + i * 16 + fr) * LDT + kc * 32 + kb * 8];
#pragma unroll
            for (int j = 0; j < 4; ++j)
                bF[j] = *(const f16x8*)&Bs[(wc * 64 + j * 16 + fr) * LDT + kc * 32 + kb * 8];
#pragma unroll
            for (int i = 0; i < 4; ++i)
#pragma unroll
                for (int j = 0; j < 4; ++j)
                    acc[i][j] = __builtin_amdgcn_mfma_f32_16x16x32_f16(
                        aF[i], bF[j], acc[i][j], 0, 0, 0);
        }
    }
#undef LOAD_STEP
}

// QKV: writes Q,K fp16 (b,h,s,d); V transposed fp16 (b,h,d,s).
__global__ __launch_bounds__(256, 2) void qkv_mfma(
    const f16* __restrict__ xh, const f16* __restrict__ wh,
    const float* __restrict__ bq, const float* __restrict__ bk,
    const float* __restrict__ bv,
    f16* __restrict__ qh, f16* __restrict__ kh, f16* __restrict__ vth)
{
    const int z = blockIdx.z;
    const f16* Bm = wh + ((size_t)z << 20);
    const float* bias = (z == 0) ? bq : (z == 1) ? bk : bv;
    const int m0 = blockIdx.y * BM, n0 = blockIdx.x * BN;
    f32x4 acc[4][4];
    mfma_gemm_tile(xh, Bm, m0, n0, acc);

    const int lane = threadIdx.x & 63;
    const int w    = threadIdx.x >> 6;
    const int wr   = w >> 1, wc = w & 1;
    const int fr   = lane & 15;
    const int rg   = lane >> 4;
#pragma unroll
    for (int i = 0; i < 4; ++i)
#pragma unroll
        for (int j = 0; j < 4; ++j) {
            int n = n0 + wc * 64 + j * 16 + fr;
            int h = n >> 6, d = n & 63;
            float bv_ = bias[n];
            int m_base = m0 + wr * 64 + i * 16 + rg * 4;
            int b = m_base >> 10, s0 = m_base & 1023;
            if (z < 2) {
                f16* p = (z == 0) ? qh : kh;
#pragma unroll
                for (int r = 0; r < 4; ++r) {
                    float v = acc[i][j][r] + bv_;
                    p[((size_t)((b * HEADS + h) * SEQ + s0 + r)) * HD + d] = (f16)v;
                }
            } else {
                f16x4 h4;
                h4.x = (f16)(acc[i][j][0] + bv_);
                h4.y = (f16)(acc[i][j][1] + bv_);
                h4.z = (f16)(acc[i][j][2] + bv_);
                h4.w = (f16)(acc[i][j][3] + bv_);
                size_t a = ((size_t)((b * HEADS + h) * HD + d)) * SEQ + s0;
                *(f16x4*)(vth + a) = h4;
            }
        }
}

// OPROJ: ctx fp16 @ wo^T + bo -> out fp32
__global__ __launch_bounds__(256, 2) void oproj_mfma(
    const f16* __restrict__ ch, const f16* __restrict__ wh,
    const float* __restrict__ bo, float* __restrict__ out)
{
    const f16* Bm = wh + ((size_t)3 << 20);
    const int m0 = blockIdx.y * BM, n0 = blockIdx.x * BN;
    f32x4 acc[4][4];
    mfma_gemm_tile(ch, Bm, m0, n0, acc);

    const int lane = threadIdx.x & 63;
    const int w    = threadIdx.x >> 6;
    const int wr   = w >> 1, wc = w & 1;
    const int fr   = lane & 15;
    const int rg   = lane >> 4;
#pragma unroll
    for (int i = 0; i < 4; ++i)
#pragma unroll
        for (int j = 0; j < 4; ++j) {
            int n = n0 + wc * 64 + j * 16 + fr;
            float bv_ = bo[n];
#pragma unroll
            for (int r = 0; r < 4; ++r) {
                int m = m0 + wr * 64 + i * 16 + rg * 4 + r;
                out[(size_t)m * EMB + n] = acc[i][j][r] + bv_;
            }
        }
}

// ---------------- attention: fp16 MFMA, 32 q-rows / 8 waves ----------------
// Round-9 structure; round-10 change: attn output written COALESCED via LDS
// read-back of the swizzled PT tile (f16x4 -> float4 nontemporal, full
// 128B lines per wave) instead of per-lane scalar f32 stores (64B segments,
// ~2x HBM write-efficiency loss measured as attn ~2x over its write floor).
__global__ __launch_bounds__(512, 4) void attn_kernel(
    const f16* __restrict__ qh, const f16* __restrict__ kh,
    const f16* __restrict__ vth,
    float* __restrict__ attn, f16* __restrict__ ch)
{
    __shared__ f16 SM[12288];   // 24 KB: VT [0,8192), PT [8192,12288); K [0,4096)
    __shared__ float RMAX[8][16];
    __shared__ float RSUM[8][16];

    const int lid = blockIdx.y * gridDim.x + blockIdx.x;  // 0..2047
    const int xs  = lid & 7;
    const int jj  = lid >> 3;
    const int bh  = xs * 8 + (jj >> 5);
    const int qt  = jj & 31;

    const int tid  = threadIdx.x;
    const int w    = tid >> 6;
    const int grp  = w >> 2;
    const int wg   = w & 3;
    const int lane = tid & 63;
    const int c    = lane & 15;
    const int g    = lane >> 4;

    const size_t bhS = (size_t)bh * SEQ;

    // Q A-frags: lane holds q-row = qt*32 + grp*16 + c
    f16x8 Q0, Q1;
    {
        size_t qb = (bhS + qt * 32 + grp * 16 + c) * HD + g * 8;
        Q0 = *(const f16x8*)(qh + qb);
        Q1 = *(const f16x8*)(qh + qb + 32);
    }

    f32x4 s4[16];
#pragma unroll
    for (int kt = 0; kt < 16; ++kt) s4[kt] = (f32x4){0.f, 0.f, 0.f, 0.f};

    // ---- phase 1: QK^T, K tile (64x64 f16) staged by all 512 threads ----
    const int srow = tid >> 3;           // 0..63
    const int sch  = tid & 7;
    const int sswz = sch ^ (srow & 7);
#pragma unroll
    for (int kt = 0; kt < 16; ++kt) {
        size_t ga = (bhS + kt * 64 + srow) * HD + sch * 8;
        f16x8 sh = *(const f16x8*)(kh + ga);
        __syncthreads();   // prev tile frag reads done
        *(f16x8*)&SM[srow * 64 + sswz * 8] = sh;
        __syncthreads();
        const int krow = wg * 16 + c;
        const int cs   = c & 7;
        f16x8 B0 = *(const f16x8*)&SM[krow * 64 + ((0 + g) ^ cs) * 8];
        f16x8 B1 = *(const f16x8*)&SM[krow * 64 + ((4 + g) ^ cs) * 8];
        s4[kt] = __builtin_amdgcn_mfma_f32_16x16x32_f16(Q0, B0, s4[kt], 0, 0, 0);
        s4[kt] = __builtin_amdgcn_mfma_f32_16x16x32_f16(Q1, B1, s4[kt], 0, 0, 0);
    }

    // ---- softmax (per 4-wave group) ----
    float m_[4], l_[4];
#pragma unroll
    for (int r = 0; r < 4; ++r) {
        float mm = -1e30f;
#pragma unroll
        for (int kt = 0; kt < 16; ++kt) {
            s4[kt][r] *= 0.125f;
            mm = fmaxf(mm, s4[kt][r]);
        }
        m_[r] = mm;
    }
#pragma unroll
    for (int off = 1; off < 16; off <<= 1)
#pragma unroll
        for (int r = 0; r < 4; ++r) m_[r] = fmaxf(m_[r], __shfl_xor(m_[r], off));
    if (c == 0) {
#pragma unroll
        for (int r = 0; r < 4; ++r) RMAX[w][g * 4 + r] = m_[r];
    }
    __syncthreads();
#pragma unroll
    for (int r = 0; r < 4; ++r)
        m_[r] = fmaxf(fmaxf(RMAX[grp * 4 + 0][g * 4 + r], RMAX[grp * 4 + 1][g * 4 + r]),
                      fmaxf(RMAX[grp * 4 + 2][g * 4 + r], RMAX[grp * 4 + 3][g * 4 + r]));
#pragma unroll
    for (int r = 0; r < 4; ++r) {
        float ss = 0.f;
#pragma unroll
        for (int kt = 0; kt < 16; ++kt) {
            float p = __expf(s4[kt][r] - m_[r]);
            s4[kt][r] = p;
            ss += p;
        }
        l_[r] = ss;
    }
#pragma unroll
    for (int off = 1; off < 16; off <<= 1)
#pragma unroll
        for (int r = 0; r < 4; ++r) l_[r] += __shfl_xor(l_[r], off);
    if (c == 0) {
#pragma unroll
        for (int r = 0; r < 4; ++r) RSUM[w][g * 4 + r] = l_[r];
    }
    __syncthreads();
#pragma unroll
    for (int r = 0; r < 4; ++r)
        l_[r] = 1.f / (RSUM[grp * 4 + 0][g * 4 + r] + RSUM[grp * 4 + 1][g * 4 + r] +
                       RSUM[grp * 4 + 2][g * 4 + r] + RSUM[grp * 4 + 3][g * 4 + r]);

    // ---- phase 3: PV + coalesced attn write (8 chunks of 128 k) ----
    f32x4 ctx = (f32x4){0.f, 0.f, 0.f, 0.f};
    float* ap = attn + (bhS + qt * 32) * SEQ;
    const int vrow0 = tid >> 4;          // 0..31 (t adds 32)
    const int vch   = tid & 15;

#pragma unroll
    for (int ct = 0; ct < 8; ++ct) {
        f16x8 vv[2];
#pragma unroll
        for (int t = 0; t < 2; ++t) {
            int drow = vrow0 + t * 32;
            size_t ga = ((size_t)bh * HD + drow) * SEQ + ct * 128 + vch * 8;
            vv[t] = *(const f16x8*)(vth + ga);
        }
        __syncthreads();   // prev chunk frag/PT-store reads done
#pragma unroll
        for (int t = 0; t < 2; ++t) {
            int drow = vrow0 + t * 32;
            int swz = vch ^ (drow & 7);
            *(f16x8*)&SM[drow * 128 + swz * 8] = vv[t];
        }
        // normalized P -> PT fp16 (swizzled A-frag layout)
#pragma unroll
        for (int kt2 = 0; kt2 < 2; ++kt2) {
            const int ktg = ct * 2 + kt2;
            const int chh = (kt2 * 64 + wg * 16 + c) >> 3;
#pragma unroll
            for (int r = 0; r < 4; ++r) {
                const int q = g * 4 + r;
                float val = s4[ktg][r] * l_[r];
                int schP = chh ^ q;
                SM[8192 + (grp * 16 + q) * 128 + schP * 8 + (c & 7)] = (f16)val;
            }
        }
        __syncthreads();
        // PV: A = P frags (own group), B = V^T frags (shared)
        const int drow = wg * 16 + c;
        const int ds7  = drow & 7;
#pragma unroll
        for (int ks = 0; ks < 4; ++ks) {
            f16x8 Vh = *(const f16x8*)&SM[drow * 128 + ((ks * 4 + g) ^ ds7) * 8];
            f16x8 Pa = *(const f16x8*)&SM[8192 + (grp * 16 + c) * 128 + (((ks * 4 + g) ^ c) & 15) * 8];
            ctx = __builtin_amdgcn_mfma_f32_16x16x32_f16(Pa, Vh, ctx, 0, 0, 0);
        }
        // coalesced attn write: read PT back, convert, float4 nontemporal.
        // wave covers 2 full rows x 512B -> full 128B lines.
#pragma unroll
        for (int t = 0; t < 2; ++t) {
            int idx = tid + (t << 9);        // 0..1023
            int row = idx >> 5;              // 0..31
            int c4  = idx & 31;              // float4 slot in 128 cols
            int col = c4 << 2;
            int swz = (col >> 3) ^ (row & 15);
            f16x4 pv = *(const f16x4*)&SM[8192 + row * 128 + swz * 8 + (col & 7)];
            vf4 o = __builtin_convertvector(pv, vf4);
            __builtin_nontemporal_store(o,
                (vf4*)(ap + (size_t)row * SEQ + ct * 128 + col));
        }
    }

    // ---- epilogue: ctx -> ch (merged (b,s,h*d), fp16) ----
    {
        int b = bh >> 4, h = bh & 15;
#pragma unroll
        for (int r = 0; r < 4; ++r) {
            int qrow = qt * 32 + grp * 16 + g * 4 + r;
            size_t a = (((size_t)(b * SEQ + qrow)) << 10) + h * HD + wg * 16 + c;
            ch[a] = (f16)ctx[r];
        }
    }
}

extern "C" void kernel_launch(void* const* d_in, const int* in_sizes, int n_in,
                              void* d_out, int out_size, void* d_ws, size_t ws_size,
                              hipStream_t stream) {
    const float* x  = (const float*)d_in[0];
    const float* wq = (const float*)d_in[1];
    const float* bq = (const float*)d_in[2];
    const float* wk = (const float*)d_in[3];
    const float* bk = (const float*)d_in[4];
    const float* wv = (const float*)d_in[5];
    const float* bv = (const float*)d_in[6];
    const float* wo = (const float*)d_in[7];
    const float* bo = (const float*)d_in[8];

    float* out      = (float*)d_out;
    float* attn_out = out + (size_t)BATCH * SEQ * EMB;

    const size_t MK = (size_t)MTOT * 1024;
    f16* ws16 = (f16*)d_ws;
    f16* xh  = ws16;                     // reused as ch after qkv
    f16* wh  = xh + MK;                  // 4 planes of 1024x1024
    f16* qh  = wh + ((size_t)4 << 20);
    f16* kh  = qh + MK;
    f16* vth = kh + MK;
    f16* ch  = xh;

    convert_all<<<8192, 256, 0, stream>>>(x, wq, wk, wv, wo, xh, wh);

    qkv_mfma<<<dim3(EMB / BN, MTOT / BM, 3), 256, 0, stream>>>(
        xh, wh, bq, bk, bv, qh, kh, vth);

    attn_kernel<<<dim3(SEQ / 32, BATCH * HEADS), 512, 0, stream>>>(
        qh, kh, vth, attn_out, ch);

    oproj_mfma<<<dim3(EMB / BN, MTOT / BM), 256, 0, stream>>>(
        ch, wh, bo, out);
}

// Round 11
// 138.056 us; speedup vs baseline: 2.9029x; 1.0732x over previous
//
#include <hip/hip_runtime.h>
#include <math.h>

#define BATCH 4
#define SEQ   1024
#define EMB   1024
#define HEADS 16
#define HD    64
#define MTOT  (BATCH*SEQ)   // 4096

typedef float    f32x4 __attribute__((ext_vector_type(4)));
typedef float    vf4   __attribute__((ext_vector_type(4)));
typedef _Float16 f16;
typedef _Float16 f16x4 __attribute__((ext_vector_type(4)));
typedef _Float16 f16x8 __attribute__((ext_vector_type(8)));

// ---- conversion: x (4096 rows) + 4 weights (4096 rows) -> fp16 ------------
__global__ __launch_bounds__(256) void convert_all(
    const float* __restrict__ x,
    const float* __restrict__ wq, const float* __restrict__ wk,
    const float* __restrict__ wv, const float* __restrict__ wo,
    f16* __restrict__ xh, f16* __restrict__ wh)
{
    const int bid = blockIdx.x;          // 0..8191
    const float* src;
    f16* dst;
    if (bid < 4096) {
        src = x + ((size_t)bid << 10);
        dst = xh + ((size_t)bid << 10);
    } else {
        int t  = bid - 4096;
        int mi = t >> 10, r = t & 1023;
        const float* in = (mi == 0) ? wq : (mi == 1) ? wk : (mi == 2) ? wv : wo;
        src = in + ((size_t)r << 10);
        dst = wh + ((size_t)mi << 20) + ((size_t)r << 10);
    }
    int o = threadIdx.x << 2;
    float4 v = *(const float4*)(src + o);
    f16x4 h;
    h.x = (f16)v.x; h.y = (f16)v.y; h.z = (f16)v.z; h.w = (f16)v.w;
    *(f16x4*)(dst + o) = h;
}

// ---- fp16 single-pass MFMA GEMM tile: C = A @ W^T -------------------------
#define BM  128
#define BN  128
#define LDT 72   // f16 elems per padded LDS row

__device__ __forceinline__ void mfma_gemm_tile(
    const f16* __restrict__ A, const f16* __restrict__ B,
    int m0, int n0, f32x4 acc[4][4], f16* SMEM)
{
    f16* As = SMEM;
    f16* Bs = SMEM + BM * LDT;
    const int tid  = threadIdx.x;
    const int lane = tid & 63;
    const int w    = tid >> 6;
    const int wr   = w >> 1, wc = w & 1;
    const int fr   = lane & 15;
    const int kb   = lane >> 4;

#pragma unroll
    for (int i = 0; i < 4; ++i)
#pragma unroll
        for (int j = 0; j < 4; ++j) acc[i][j] = (f32x4){0.f, 0.f, 0.f, 0.f};

    f16x8 ra[4], rb[4];
#define LOAD_STEP(KT)                                                          \
    {                                                                          \
        int k0 = (KT) * 64;                                                    \
        _Pragma("unroll")                                                      \
        for (int i = 0; i < 4; ++i) {                                          \
            int c = tid + (i << 8);                                            \
            int row = c >> 3, cc = (c & 7) << 3;                               \
            ra[i] = *(const f16x8*)(A + ((size_t)(m0 + row) << 10) + k0 + cc); \
            rb[i] = *(const f16x8*)(B + ((size_t)(n0 + row) << 10) + k0 + cc); \
        }                                                                      \
    }

    LOAD_STEP(0);
    for (int kt = 0; kt < 16; ++kt) {
        __syncthreads();
#pragma unroll
        for (int i = 0; i < 4; ++i) {
            int c = tid + (i << 8);
            int row = c >> 3, cc = (c & 7) << 3;
            *(f16x8*)&As[row * LDT + cc] = ra[i];
            *(f16x8*)&Bs[row * LDT + cc] = rb[i];
        }
        if (kt + 1 < 16) LOAD_STEP(kt + 1);
        __syncthreads();
#pragma unroll
        for (int kc = 0; kc < 2; ++kc) {
            f16x8 aF[4], bF[4];
#pragma unroll
            for (int i = 0; i < 4; ++i)
                aF[i] = *(const f16x8*)&As[(wr * 64 + i * 16 + fr) * LDT + kc * 32 + kb * 8];
#pragma unroll
            for (int j = 0; j < 4; ++j)
                bF[j] = *(const f16x8*)&Bs[(wc * 64 + j * 16 + fr) * LDT + kc * 32 + kb * 8];
#pragma unroll
            for (int i = 0; i < 4; ++i)
#pragma unroll
                for (int j = 0; j < 4; ++j)
                    acc[i][j] = __builtin_amdgcn_mfma_f32_16x16x32_f16(
                        aF[i], bF[j], acc[i][j], 0, 0, 0);
        }
    }
#undef LOAD_STEP
}

// QKV: writes Q,K fp16 (b,h,s,d); V transposed fp16 (b,h,d,s).
// Epilogue LDS-bounces the C-tile so all global stores are f16x8 coalesced.
__global__ __launch_bounds__(256, 2) void qkv_mfma(
    const f16* __restrict__ xh, const f16* __restrict__ wh,
    const float* __restrict__ bq, const float* __restrict__ bk,
    const float* __restrict__ bv,
    f16* __restrict__ qh, f16* __restrict__ kh, f16* __restrict__ vth)
{
    __shared__ __align__(16) f16 SMEM[2 * BM * LDT];   // 36 KB
    const int z = blockIdx.z;
    const f16* Bm = wh + ((size_t)z << 20);
    const float* bias = (z == 0) ? bq : (z == 1) ? bk : bv;
    const int m0 = blockIdx.y * BM, n0 = blockIdx.x * BN;
    f32x4 acc[4][4];
    mfma_gemm_tile(xh, Bm, m0, n0, acc, SMEM);

    const int tid  = threadIdx.x;
    const int lane = tid & 63;
    const int w    = tid >> 6;
    const int wr   = w >> 1, wc = w & 1;
    const int fr   = lane & 15;
    const int rg   = lane >> 4;
    const int LDC  = 136;
    const int b = m0 >> 10, sbase = m0 & 1023;

    __syncthreads();   // gemm LDS reads done
    if (z < 2) {
        f16* p = (z == 0) ? qh : kh;
#pragma unroll
        for (int i = 0; i < 4; ++i)
#pragma unroll
            for (int j = 0; j < 4; ++j) {
                int nn = wc * 64 + j * 16 + fr;
                float bv_ = bias[n0 + nn];
#pragma unroll
                for (int r = 0; r < 4; ++r) {
                    int mm = wr * 64 + i * 16 + rg * 4 + r;
                    SMEM[mm * LDC + nn] = (f16)(acc[i][j][r] + bv_);
                }
            }
        __syncthreads();
#pragma unroll
        for (int t = 0; t < 8; ++t) {
            int idx = tid + (t << 8);
            int row = idx >> 4, ch = idx & 15;
            int n8 = n0 + ch * 8;
            int h = n8 >> 6, d = n8 & 63;
            f16x8 v = *(const f16x8*)&SMEM[row * LDC + ch * 8];
            *(f16x8*)(p + ((size_t)((b * HEADS + h) * SEQ + sbase + row)) * HD + d) = v;
        }
    } else {
        // transposed bounce: SMEM[n][m] so V stores are s-contiguous
#pragma unroll
        for (int i = 0; i < 4; ++i)
#pragma unroll
            for (int j = 0; j < 4; ++j) {
                int nn = wc * 64 + j * 16 + fr;
                float bv_ = bias[n0 + nn];
#pragma unroll
                for (int r = 0; r < 4; ++r) {
                    int mm = wr * 64 + i * 16 + rg * 4 + r;
                    SMEM[nn * LDC + mm] = (f16)(acc[i][j][r] + bv_);
                }
            }
        __syncthreads();
#pragma unroll
        for (int t = 0; t < 8; ++t) {
            int idx = tid + (t << 8);
            int col = idx >> 4, mch = idx & 15;
            int n8 = n0 + col;
            int h = n8 >> 6, d = n8 & 63;
            f16x8 v = *(const f16x8*)&SMEM[col * LDC + mch * 8];
            *(f16x8*)(vth + ((size_t)((b * HEADS + h) * HD + d)) * SEQ + sbase + mch * 8) = v;
        }
    }
}

// OPROJ: ctx fp16 @ wo^T + bo -> out fp32, LDS-bounced float4 stores.
__global__ __launch_bounds__(256, 2) void oproj_mfma(
    const f16* __restrict__ ch, const f16* __restrict__ wh,
    const float* __restrict__ bo, float* __restrict__ out)
{
    __shared__ __align__(16) f16 SMEM[2 * BM * LDT];
    const f16* Bm = wh + ((size_t)3 << 20);
    const int m0 = blockIdx.y * BM, n0 = blockIdx.x * BN;
    f32x4 acc[4][4];
    mfma_gemm_tile(ch, Bm, m0, n0, acc, SMEM);

    const int tid  = threadIdx.x;
    const int lane = tid & 63;
    const int w    = tid >> 6;
    const int wr   = w >> 1, wc = w & 1;
    const int fr   = lane & 15;
    const int rg   = lane >> 4;
    float* Cf = (float*)SMEM;            // 64 x 132 fp32 half-tile
    const int LDCf = 132;

#pragma unroll
    for (int half = 0; half < 2; ++half) {
        __syncthreads();
        if (wr == half) {
#pragma unroll
            for (int i = 0; i < 4; ++i)
#pragma unroll
                for (int j = 0; j < 4; ++j) {
                    int nn = wc * 64 + j * 16 + fr;
                    float bv_ = bo[n0 + nn];
#pragma unroll
                    for (int r = 0; r < 4; ++r)
                        Cf[(i * 16 + rg * 4 + r) * LDCf + nn] = acc[i][j][r] + bv_;
                }
        }
        __syncthreads();
#pragma unroll
        for (int t = 0; t < 8; ++t) {
            int idx = tid + (t << 8);
            int row = idx >> 5, c4 = (idx & 31) << 2;
            vf4 v = *(const vf4*)&Cf[row * LDCf + c4];
            __builtin_nontemporal_store(v,
                (vf4*)(out + (size_t)(m0 + half * 64 + row) * EMB + n0 + c4));
        }
    }
}

// ---------------- attention: fp16 MFMA, 32 q-rows / 8 waves ----------------
// Round-11 changes: phase-1 K staged in 128-row chunks (8 iters, half the
// barriers) with explicit next-chunk register prefetch issued before the
// compute barrier; phase-3 V prefetched one chunk ahead (T14).
__global__ __launch_bounds__(512, 4) void attn_kernel(
    const f16* __restrict__ qh, const f16* __restrict__ kh,
    const f16* __restrict__ vth,
    float* __restrict__ attn, f16* __restrict__ ch)
{
    __shared__ f16 SM[12288];   // 24 KB: K/VT [0,8192), PT [8192,12288)
    __shared__ float RMAX[8][16];
    __shared__ float RSUM[8][16];

    const int lid = blockIdx.y * gridDim.x + blockIdx.x;  // 0..2047
    const int xs  = lid & 7;
    const int jj  = lid >> 3;
    const int bh  = xs * 8 + (jj >> 5);
    const int qt  = jj & 31;

    const int tid  = threadIdx.x;
    const int w    = tid >> 6;
    const int grp  = w >> 2;
    const int wg   = w & 3;
    const int lane = tid & 63;
    const int c    = lane & 15;
    const int g    = lane >> 4;

    const size_t bhS = (size_t)bh * SEQ;

    // Q A-frags: lane holds q-row = qt*32 + grp*16 + c
    f16x8 Q0, Q1;
    {
        size_t qb = (bhS + qt * 32 + grp * 16 + c) * HD + g * 8;
        Q0 = *(const f16x8*)(qh + qb);
        Q1 = *(const f16x8*)(qh + qb + 32);
    }

    f32x4 s4[16];
#pragma unroll
    for (int kt = 0; kt < 16; ++kt) s4[kt] = (f32x4){0.f, 0.f, 0.f, 0.f};

    // ---- phase 1: QK^T, K in 128-row chunks, register prefetch ----
    const int srow = tid >> 3;           // 0..63
    const int sch  = tid & 7;
    f16x8 kc0, kc1, kn0, kn1;
    {
        size_t ga = (bhS + srow) * HD + sch * 8;
        kc0 = *(const f16x8*)(kh + ga);
        kc1 = *(const f16x8*)(kh + ga + (size_t)64 * HD);
    }
#pragma unroll
    for (int kt2 = 0; kt2 < 8; ++kt2) {
        __syncthreads();   // prev chunk frag reads done
        {
            int r1 = srow + 64;
            *(f16x8*)&SM[srow * 64 + (sch ^ (srow & 7)) * 8] = kc0;
            *(f16x8*)&SM[r1 * 64 + (sch ^ (r1 & 7)) * 8]     = kc1;
        }
        if (kt2 < 7) {
            size_t ga = (bhS + (kt2 + 1) * 128 + srow) * HD + sch * 8;
            kn0 = *(const f16x8*)(kh + ga);
            kn1 = *(const f16x8*)(kh + ga + (size_t)64 * HD);
        }
        __syncthreads();
#pragma unroll
        for (int half = 0; half < 2; ++half) {
            const int krow = half * 64 + wg * 16 + c;
            const int ks7  = krow & 7;
            f16x8 B0 = *(const f16x8*)&SM[krow * 64 + ((0 + g) ^ ks7) * 8];
            f16x8 B1 = *(const f16x8*)&SM[krow * 64 + ((4 + g) ^ ks7) * 8];
            s4[kt2 * 2 + half] = __builtin_amdgcn_mfma_f32_16x16x32_f16(
                Q0, B0, s4[kt2 * 2 + half], 0, 0, 0);
            s4[kt2 * 2 + half] = __builtin_amdgcn_mfma_f32_16x16x32_f16(
                Q1, B1, s4[kt2 * 2 + half], 0, 0, 0);
        }
        kc0 = kn0; kc1 = kn1;
    }

    // ---- softmax (per 4-wave group) ----
    float m_[4], l_[4];
#pragma unroll
    for (int r = 0; r < 4; ++r) {
        float mm = -1e30f;
#pragma unroll
        for (int kt = 0; kt < 16; ++kt) {
            s4[kt][r] *= 0.125f;
            mm = fmaxf(mm, s4[kt][r]);
        }
        m_[r] = mm;
    }
#pragma unroll
    for (int off = 1; off < 16; off <<= 1)
#pragma unroll
        for (int r = 0; r < 4; ++r) m_[r] = fmaxf(m_[r], __shfl_xor(m_[r], off));
    if (c == 0) {
#pragma unroll
        for (int r = 0; r < 4; ++r) RMAX[w][g * 4 + r] = m_[r];
    }
    __syncthreads();
#pragma unroll
    for (int r = 0; r < 4; ++r)
        m_[r] = fmaxf(fmaxf(RMAX[grp * 4 + 0][g * 4 + r], RMAX[grp * 4 + 1][g * 4 + r]),
                      fmaxf(RMAX[grp * 4 + 2][g * 4 + r], RMAX[grp * 4 + 3][g * 4 + r]));
#pragma unroll
    for (int r = 0; r < 4; ++r) {
        float ss = 0.f;
#pragma unroll
        for (int kt = 0; kt < 16; ++kt) {
            float p = __expf(s4[kt][r] - m_[r]);
            s4[kt][r] = p;
            ss += p;
        }
        l_[r] = ss;
    }
#pragma unroll
    for (int off = 1; off < 16; off <<= 1)
#pragma unroll
        for (int r = 0; r < 4; ++r) l_[r] += __shfl_xor(l_[r], off);
    if (c == 0) {
#pragma unroll
        for (int r = 0; r < 4; ++r) RSUM[w][g * 4 + r] = l_[r];
    }
    __syncthreads();
#pragma unroll
    for (int r = 0; r < 4; ++r)
        l_[r] = 1.f / (RSUM[grp * 4 + 0][g * 4 + r] + RSUM[grp * 4 + 1][g * 4 + r] +
                       RSUM[grp * 4 + 2][g * 4 + r] + RSUM[grp * 4 + 3][g * 4 + r]);

    // ---- phase 3: PV + coalesced attn write (8 chunks of 128 k), V prefetch
    f32x4 ctx = (f32x4){0.f, 0.f, 0.f, 0.f};
    float* ap = attn + (bhS + qt * 32) * SEQ;
    const int vrow0 = tid >> 4;          // 0..31 (t adds 32)
    const int vch   = tid & 15;

    f16x8 vc[2], vn[2];
#pragma unroll
    for (int t = 0; t < 2; ++t) {
        int drow = vrow0 + t * 32;
        vc[t] = *(const f16x8*)(vth + ((size_t)bh * HD + drow) * SEQ + vch * 8);
    }
#pragma unroll
    for (int ct = 0; ct < 8; ++ct) {
        __syncthreads();   // prev chunk frag/PT reads done (also phase-1 K reads)
#pragma unroll
        for (int t = 0; t < 2; ++t) {
            int drow = vrow0 + t * 32;
            int swz = vch ^ (drow & 7);
            *(f16x8*)&SM[drow * 128 + swz * 8] = vc[t];
        }
        if (ct < 7) {
#pragma unroll
            for (int t = 0; t < 2; ++t) {
                int drow = vrow0 + t * 32;
                vn[t] = *(const f16x8*)(vth + ((size_t)bh * HD + drow) * SEQ +
                                        (ct + 1) * 128 + vch * 8);
            }
        }
        // normalized P -> PT fp16 (swizzled A-frag layout)
#pragma unroll
        for (int kt2 = 0; kt2 < 2; ++kt2) {
            const int ktg = ct * 2 + kt2;
            const int chh = (kt2 * 64 + wg * 16 + c) >> 3;
#pragma unroll
            for (int r = 0; r < 4; ++r) {
                const int q = g * 4 + r;
                float val = s4[ktg][r] * l_[r];
                int schP = chh ^ q;
                SM[8192 + (grp * 16 + q) * 128 + schP * 8 + (c & 7)] = (f16)val;
            }
        }
        __syncthreads();
        // PV: A = P frags (own group), B = V^T frags (shared)
        const int drow = wg * 16 + c;
        const int ds7  = drow & 7;
#pragma unroll
        for (int ks = 0; ks < 4; ++ks) {
            f16x8 Vh = *(const f16x8*)&SM[drow * 128 + ((ks * 4 + g) ^ ds7) * 8];
            f16x8 Pa = *(const f16x8*)&SM[8192 + (grp * 16 + c) * 128 + (((ks * 4 + g) ^ c) & 15) * 8];
            ctx = __builtin_amdgcn_mfma_f32_16x16x32_f16(Pa, Vh, ctx, 0, 0, 0);
        }
        // coalesced attn write: read PT back, convert, float4 nontemporal
#pragma unroll
        for (int t = 0; t < 2; ++t) {
            int idx = tid + (t << 9);        // 0..1023
            int row = idx >> 5;              // 0..31
            int c4  = idx & 31;
            int col = c4 << 2;
            int swz = (col >> 3) ^ (row & 15);
            f16x4 pv = *(const f16x4*)&SM[8192 + row * 128 + swz * 8 + (col & 7)];
            vf4 o = __builtin_convertvector(pv, vf4);
            __builtin_nontemporal_store(o,
                (vf4*)(ap + (size_t)row * SEQ + ct * 128 + col));
        }
        vc[0] = vn[0]; vc[1] = vn[1];
    }

    // ---- epilogue: ctx -> ch (merged (b,s,h*d), fp16) ----
    {
        int b = bh >> 4, h = bh & 15;
#pragma unroll
        for (int r = 0; r < 4; ++r) {
            int qrow = qt * 32 + grp * 16 + g * 4 + r;
            size_t a = (((size_t)(b * SEQ + qrow)) << 10) + h * HD + wg * 16 + c;
            ch[a] = (f16)ctx[r];
        }
    }
}

extern "C" void kernel_launch(void* const* d_in, const int* in_sizes, int n_in,
                              void* d_out, int out_size, void* d_ws, size_t ws_size,
                              hipStream_t stream) {
    const float* x  = (const float*)d_in[0];
    const float* wq = (const float*)d_in[1];
    const float* bq = (const float*)d_in[2];
    const float* wk = (const float*)d_in[3];
    const float* bk = (const float*)d_in[4];
    const float* wv = (const float*)d_in[5];
    const float* bv = (const float*)d_in[6];
    const float* wo = (const float*)d_in[7];
    const float* bo = (const float*)d_in[8];

    float* out      = (float*)d_out;
    float* attn_out = out + (size_t)BATCH * SEQ * EMB;

    const size_t MK = (size_t)MTOT * 1024;
    f16* ws16 = (f16*)d_ws;
    f16* xh  = ws16;                     // reused as ch after qkv
    f16* wh  = xh + MK;                  // 4 planes of 1024x1024
    f16* qh  = wh + ((size_t)4 << 20);
    f16* kh  = qh + MK;
    f16* vth = kh + MK;
    f16* ch  = xh;

    convert_all<<<8192, 256, 0, stream>>>(x, wq, wk, wv, wo, xh, wh);

    qkv_mfma<<<dim3(EMB / BN, MTOT / BM, 3), 256, 0, stream>>>(
        xh, wh, bq, bk, bv, qh, kh, vth);

    attn_kernel<<<dim3(SEQ / 32, BATCH * HEADS), 512, 0, stream>>>(
        qh, kh, vth, attn_out, ch);

    oproj_mfma<<<dim3(EMB / BN, MTOT / BM), 256, 0, stream>>>(
        ch, wh, bo, out);
}